// Round 6
// baseline (1944.907 us; speedup 1.0000x reference)
//
#include <hip/hip_runtime.h>
#include <math.h>

#define NN 2048
#define DIMF 256
#define HIDN 128
#define NG 8
#define NEDGES 32768
#define W32 32
#define TRI_CAP 131072
#define TRI_LDS 4864

typedef unsigned long long u64;
typedef unsigned char u8;
typedef unsigned short u16;

// ---------------- build adjacency ----------------
__global__ void k_init(u64* __restrict__ rowbits, int* __restrict__ segstart) {
  int i = blockIdx.x * blockDim.x + threadIdx.x;
  for (int k = i; k < NN * W32; k += gridDim.x * blockDim.x) rowbits[k] = 0ull;
  if (i <= NG) segstart[i] = NN;
}

__global__ void k_edges(const int* __restrict__ ei, u64* __restrict__ rowbits) {
  int e = blockIdx.x * blockDim.x + threadIdx.x;
  if (e >= NEDGES) return;
  int u = ei[e], v = ei[NEDGES + e];
  atomicOr(&rowbits[((size_t)u << 5) + (v >> 6)], 1ull << (v & 63));
}

// deg + segment bounds (fused)
__global__ void k_deg(const u64* __restrict__ rowbits, int* __restrict__ deg,
                      const int* __restrict__ batch, int* __restrict__ segstart) {
  int i = blockIdx.x * blockDim.x + threadIdx.x;
  if (i >= NN) return;
  int c = 0;
  for (int w = 0; w < W32; ++w) c += __popcll(rowbits[(i << 5) + w]);
  deg[i] = c;
  if (i == 0 || batch[i] != batch[i - 1]) segstart[batch[i]] = i;
}

// exclusive scan of 2048 ints -> out[0..2048]
__global__ void k_scan2048(const int* __restrict__ in, int* __restrict__ out) {
  __shared__ int part[256];
  int t = threadIdx.x;
  int v[8]; int s = 0;
  for (int k = 0; k < 8; ++k) { v[k] = in[t * 8 + k]; s += v[k]; }
  part[t] = s;
  __syncthreads();
  for (int off = 1; off < 256; off <<= 1) {
    int y = (t >= off) ? part[t - off] : 0;
    __syncthreads();
    part[t] += y;
    __syncthreads();
  }
  int run = part[t] - s;
  for (int k = 0; k < 8; ++k) { out[t * 8 + k] = run; run += v[k]; }
  if (t == 255) out[NN] = part[255];
}

// extract CSR + count triangle pairs (fused)
__global__ void k_extract(const u64* __restrict__ rowbits, const int* __restrict__ rp,
                          int* __restrict__ col, int* __restrict__ cnt) {
  int i = blockIdx.x * blockDim.x + threadIdx.x;
  if (i >= NN) return;
  const u64* ri = rowbits + ((size_t)i << 5);
  int o = rp[i];
  for (int w = 0; w < W32; ++w) {
    u64 b = ri[w];
    while (b) { col[o++] = (w << 6) + __builtin_ctzll(b); b &= b - 1; }
  }
  int c = 0;
  for (int e = rp[i]; e < o; ++e) {
    const u64* ra = rowbits + ((size_t)col[e] << 5);
    for (int w = 0; w < W32; ++w) c += __popcll(ra[w] & ri[w]);
  }
  cnt[i] = c;
}

__global__ void k_trifill(const u64* __restrict__ rowbits, const int* __restrict__ rp,
                          const int* __restrict__ col, const int* __restrict__ tp,
                          int2* __restrict__ tri) {
  int i = blockIdx.x * blockDim.x + threadIdx.x;
  if (i >= NN) return;
  const u64* ri = rowbits + ((size_t)i << 5);
  int o = tp[i];
  for (int e = rp[i]; e < rp[i + 1]; ++e) {
    int a = col[e];
    const u64* ra = rowbits + ((size_t)a << 5);
    for (int w = 0; w < W32; ++w) {
      u64 b = ra[w] & ri[w];
      while (b) {
        int j = (w << 6) + __builtin_ctzll(b);
        if (o < TRI_CAP) tri[o] = make_int2(a, j);
        ++o;
        b &= b - 1;
      }
    }
  }
}

// ---------------- entropy term ----------------
__global__ void k_V(const float* __restrict__ x, const int* __restrict__ rp,
                    const int* __restrict__ col, float* __restrict__ V) {
  int i = blockIdx.x; int t = threadIdx.x; // 256 threads = dims
  float xi = x[i * DIMF + t];
  float s1 = 0.f, s2 = 0.f;
  int r0 = rp[i], r1 = rp[i + 1];
  for (int e = r0; e < r1; ++e) {
    float xj = x[col[e] * DIMF + t];
    s1 += xj; s2 += xj * xj;
  }
  float dg = (float)(r1 - r0);
  float val = dg * xi * xi - 2.f * xi * s1 + s2;
  __shared__ double red[DIMF];
  red[t] = (double)val * (double)val;
  __syncthreads();
  for (int off = DIMF / 2; off > 0; off >>= 1) { if (t < off) red[t] += red[t + off]; __syncthreads(); }
  if (t == 0) V[i] = (float)sqrt(red[0]);
}

__global__ void k_soft(const float* __restrict__ V, const int* __restrict__ segstart,
                       float* __restrict__ ent, double* __restrict__ seggamma) {
  int g = blockIdx.x; int t = threadIdx.x;
  int s = segstart[g];
  int e = NN;
  for (int gg = g + 1; gg <= NG; ++gg) { int v = segstart[gg]; if (v < e) e = v; }
  if (s >= e) { if (t == 0) seggamma[g] = 0.0; return; }
  __shared__ float fm[256];
  __shared__ double dd[256];
  float m = -3.0e38f;
  for (int i = s + t; i < e; i += 256) m = fmaxf(m, V[i]);
  fm[t] = m; __syncthreads();
  for (int off = 128; off > 0; off >>= 1) { if (t < off) fm[t] = fmaxf(fm[t], fm[t + off]); __syncthreads(); }
  float mx = fm[0];
  __syncthreads();
  double sum = 0.0;
  for (int i = s + t; i < e; i += 256) sum += exp((double)V[i] - (double)mx);
  dd[t] = sum; __syncthreads();
  for (int off = 128; off > 0; off >>= 1) { if (t < off) dd[t] += dd[t + off]; __syncthreads(); }
  double tot = dd[0];
  __syncthreads();
  double gs = 0.0;
  for (int i = s + t; i < e; i += 256) {
    double P = exp((double)V[i] - (double)mx) / tot;
    float ev = (P > 0.0) ? (float)(-P * log(P)) : 0.f;
    ent[i] = ev;
    gs += (double)ev;
  }
  dd[t] = gs; __syncthreads();
  for (int off = 128; off > 0; off >>= 1) { if (t < off) dd[t] += dd[t + off]; __syncthreads(); }
  if (t == 0) seggamma[g] = dd[0];
}

// ---------------- GIN MLPs ----------------
__global__ void k_agg1(const float* __restrict__ ent, const int* __restrict__ rp,
                       const int* __restrict__ col, float* __restrict__ agg) {
  int i = blockIdx.x * blockDim.x + threadIdx.x;
  if (i >= NN) return;
  float a = ent[i];
  for (int e = rp[i]; e < rp[i + 1]; ++e) a += ent[col[e]];
  agg[i] = a;
}

__global__ void k_lin1(const float* __restrict__ agg, const float* __restrict__ w,
                       const float* __restrict__ b, float* __restrict__ t) {
  int idx = blockIdx.x * blockDim.x + threadIdx.x;
  if (idx >= NN * HIDN) return;
  int i = idx >> 7, k = idx & 127;
  float v = agg[i] * w[k] + b[k];
  t[idx] = v > 0.f ? v : 0.f;
}

__global__ void k_bn(const float* __restrict__ t, const float* __restrict__ g,
                     const float* __restrict__ be, float* __restrict__ scale,
                     float* __restrict__ shift) {
  int k = blockIdx.x; int tid = threadIdx.x; // 256 threads per column
  __shared__ double red[256];
  double s = 0.0;
  for (int i = tid; i < NN; i += 256) s += (double)t[i * HIDN + k];
  red[tid] = s; __syncthreads();
  for (int off = 128; off > 0; off >>= 1) { if (tid < off) red[tid] += red[tid + off]; __syncthreads(); }
  double mu = red[0] / NN;
  __syncthreads();
  double v = 0.0;
  for (int i = tid; i < NN; i += 256) { double dv = (double)t[i * HIDN + k] - mu; v += dv * dv; }
  red[tid] = v; __syncthreads();
  for (int off = 128; off > 0; off >>= 1) { if (tid < off) red[tid] += red[tid + off]; __syncthreads(); }
  if (tid == 0) {
    float var = (float)(red[0] / NN);
    float sc = g[k] / sqrtf(var + 1e-5f);
    scale[k] = sc;
    shift[k] = be[k] - (float)mu * sc;
  }
}

template<int PRE, int RELU>
__global__ void k_mm(const float* __restrict__ in, const float* __restrict__ Wm,
                     const float* __restrict__ bias, const float* __restrict__ scale,
                     const float* __restrict__ shift, float* __restrict__ out) {
  __shared__ float ti[8][HIDN];
  int r0 = blockIdx.x * 8; int t = threadIdx.x; // 128 threads
  for (int r = 0; r < 8; ++r) {
    float v = in[(r0 + r) * HIDN + t];
    if (PRE) v = v * scale[t] + shift[t];
    ti[r][t] = v;
  }
  __syncthreads();
  float acc[8];
  #pragma unroll
  for (int r = 0; r < 8; ++r) acc[r] = 0.f;
  for (int k = 0; k < HIDN; ++k) {
    float w = Wm[k * HIDN + t];
    #pragma unroll
    for (int r = 0; r < 8; ++r) acc[r] += ti[r][k] * w;
  }
  for (int r = 0; r < 8; ++r) {
    float v = acc[r] + bias[t];
    if (RELU) v = fmaxf(v, 0.f);
    out[(r0 + r) * HIDN + t] = v;
  }
}

__global__ void k_agg128(const float* __restrict__ h, const int* __restrict__ rp,
                         const int* __restrict__ col, float* __restrict__ agg) {
  int i = blockIdx.x; int t = threadIdx.x; // 128 threads
  float a = h[i * HIDN + t];
  for (int e = rp[i]; e < rp[i + 1]; ++e) a += h[col[e] * HIDN + t];
  agg[i * HIDN + t] = a;
}

__global__ void k_lin3(const float* __restrict__ tn, const float* __restrict__ scale,
                       const float* __restrict__ shift, const float* __restrict__ w32,
                       const float* __restrict__ b32, float* __restrict__ p) {
  int i = blockIdx.x; int t = threadIdx.x; // 128
  float v = (tn[i * HIDN + t] * scale[t] + shift[t]) * w32[t];
  __shared__ float red[HIDN];
  red[t] = v; __syncthreads();
  for (int off = 64; off > 0; off >>= 1) { if (t < off) red[t] += red[t + off]; __syncthreads(); }
  if (t == 0) {
    float h3 = red[0] + b32[0];
    p[i] = 1.f / (1.f + expf(-h3));
  }
}

// ---------------- greedy (fused: sort + q0/E0 + loss + speculative scan) ----------
#define DPP2(ctrl)                                                                        \
  a += __int_as_float(__builtin_amdgcn_update_dpp(0, __float_as_int(a), ctrl, 0xf, 0xf, true)); \
  b += __int_as_float(__builtin_amdgcn_update_dpp(0, __float_as_int(b), ctrl, 0xf, 0xf, true));

__device__ __forceinline__ void red2(float& a, float& b) {
  DPP2(0x111)
  DPP2(0x112)
  DPP2(0x114)
  DPP2(0x118)
  DPP2(0x142)
  DPP2(0x143)
  a = __int_as_float(__builtin_amdgcn_readlane(__float_as_int(a), 63));
  b = __int_as_float(__builtin_amdgcn_readlane(__float_as_int(b), 63));
}

// position of the 'slot'-th set bit across 16 ballot words (window base = pos); -1 if none
__device__ __forceinline__ int nthpos(const u64* B, int slot, int pos) {
  int cnt = 0, res = -1;
  #pragma unroll
  for (int i = 0; i < 16; ++i) {
    int c = __popcll(B[i]);
    if (res < 0 && cnt + c > slot) {
      u64 bb = B[i];
      int r = slot - cnt;
      for (int k = 0; k < r; ++k) bb &= bb - 1;
      res = pos + (i << 6) + (int)__builtin_ctzll(bb);
    }
    cnt += c;
  }
  return res;
}

__global__ void __launch_bounds__(1024, 1) k_greedy(
    const int* __restrict__ rp, const int* __restrict__ col,
    const int* __restrict__ tp, const int2* __restrict__ tri,
    const float* __restrict__ p, const float* __restrict__ ent,
    const double* __restrict__ seggam, double* __restrict__ scal,
    u8* __restrict__ selb_g) {
  __shared__ float2 dq[NN];           // 16 KB {d, q}
  __shared__ float2 ee[NN];           // 16 KB {ent, E}
  __shared__ u16 colL[NEDGES];        // 64 KB
  __shared__ u16 ordl[NN];            // 4 KB
  __shared__ uint2 rtP[NN];           // 16 KB {pack(i), pack(i+1)}
  __shared__ ushort2 triL[TRI_LDS];   // 19 KB
  __shared__ u64 skey[NN];            // 16 KB (sort keys)
  __shared__ unsigned decidedL[64], selL[64];
  __shared__ u64 wbalL[16];
  __shared__ unsigned maskL[2];
  __shared__ float4 svB[16];          // {S1, S2, d0, ei}
  __shared__ double svCr[16];
  __shared__ double redD[36];
  int t = threadIdx.x;
  int w = t >> 6, lane = t & 63;

  // ---- init loads ----
  for (int i = t; i < NN; i += 1024) {
    dq[i].x = p[i]; ee[i].x = ent[i];
    int tv0 = tp[i]; if (tv0 > 65535) tv0 = 65535;
    int tv1 = tp[i + 1]; if (tv1 > 65535) tv1 = 65535;
    rtP[i] = make_uint2((unsigned)rp[i] | ((unsigned)tv0 << 16),
                        (unsigned)rp[i + 1] | ((unsigned)tv1 << 16));
    unsigned bb = __float_as_uint(p[i]);
    unsigned ss = (bb & 0x80000000u) ? ~bb : (bb | 0x80000000u);
    skey[i] = ((u64)(~ss) << 32) | (unsigned)i;
  }
  for (int i = t; i < NEDGES; i += 1024) colL[i] = (u16)col[i];
  for (int i = t; i < TRI_LDS; i += 1024) {
    int2 ab = tri[i];
    triL[i] = make_ushort2((u16)(ab.x & 2047), (u16)(ab.y & 2047));
  }
  if (t < 64) { decidedL[t] = 0u; selL[t] = 0u; }
  if (t < 2) maskL[t] = 0u;
  __syncthreads();

  // ---- bitonic sort (descending p, stable) -> ordl ----
  for (int k = 2; k <= NN; k <<= 1) {
    for (int j = k >> 1; j > 0; j >>= 1) {
      for (int i = t; i < NN; i += 1024) {
        int ixj = i ^ j;
        if (ixj > i) {
          bool up = ((i & k) == 0);
          u64 a = skey[i], b = skey[ixj];
          if ((a > b) == up) { skey[i] = b; skey[ixj] = a; }
        }
      }
      __syncthreads();
    }
  }
  ordl[t] = (u16)(skey[t] & 0xffffu);
  ordl[t + 1024] = (u16)(skey[t + 1024] & 0xffffu);
  __syncthreads();

  // ---- q0 / E0 + loss partials + isolated pre-decide ----
  double la = 0.0, lb = 0.0;
  for (int i = t; i < NN; i += 1024) {
    int r0 = rtP[i].x & 0xffff, r1 = rtP[i].y & 0xffff;
    float qs = 0.f, es = 0.f;
    for (int e = r0; e < r1; ++e) {
      int j = colL[e];
      qs += dq[j].x;
      es += ee[j].x * dq[j].x;
    }
    dq[i].y = qs; ee[i].y = es;
    la += (double)ee[i].x * (double)dq[i].x;
    lb += (double)dq[i].x * (double)qs;
    if (r0 == r1) {
      atomicOr(&decidedL[i >> 5], 1u << (i & 31));
      atomicOr(&selL[i >> 5], 1u << (i & 31));
    }
  }
  // block reduce (f64 shuffles; init-only)
  for (int off = 32; off > 0; off >>= 1) { la += __shfl_down(la, off); lb += __shfl_down(lb, off); }
  if (lane == 0) { redD[w] = la; redD[16 + w] = lb; }
  __syncthreads();
  if (t == 0) {
    double A = 0.0, Bb = 0.0, gamma = 0.0;
    for (int i = 0; i < 16; ++i) { A += redD[i]; Bb += redD[16 + i]; }
    for (int g = 0; g < NG; ++g) gamma += seggam[g];
    redD[32] = gamma; redD[33] = A; redD[34] = Bb; redD[35] = gamma - A + Bb;
    scal[0] = gamma; scal[1] = A; scal[2] = Bb; scal[3] = gamma - A + Bb;
  }
  __syncthreads();
  double gamma = redD[32], loss = redD[35];
  double ed = redD[33], dAd = redD[34];
  __syncthreads();

  // ---- speculative scan with candidate compaction ----
  int pos = 0, rc = 0;
  while (pos < NN) {
    int b = rc & 1; ++rc;
    // phase A: flag undecided positions in window [pos, pos+1024)
    {
      int P = pos + t;
      int f = 0;
      if (P < NN) {
        int ix = ordl[P];
        f = !((decidedL[ix >> 5] >> (ix & 31)) & 1u);
      }
      u64 bal = __ballot(f);
      if (lane == 0) wbalL[w] = bal;
    }
    __syncthreads();
    u64 B[16];
    #pragma unroll
    for (int i = 0; i < 16; ++i) B[i] = wbalL[i];
    int total = 0;
    #pragma unroll
    for (int i = 0; i < 16; ++i) total += __popcll(B[i]);
    // eval: wave w takes the w-th undecided position
    int myP = nthpos(B, w, pos);
    if (myP >= 0) {
      int idx = ordl[myP];
      uint2 rt = rtP[idx];
      int r0 = rt.x & 0xffff, r1 = rt.y & 0xffff;
      int t0 = rt.x >> 16, t1 = rt.y >> 16;
      float2 dqi = dq[idx];
      float2 eei = ee[idx];
      float s2 = 0.f, st = 0.f;
      for (int e = r0 + lane; e < r1; e += 64) {
        float2 v = dq[colL[e]];
        s2 -= v.y * v.x;
      }
      if (t1 <= TRI_LDS) {
        for (int e = t0 + lane; e < t1; e += 64) {
          ushort2 ab = triL[e];
          st += dq[ab.x].x * dq[ab.y].x;
        }
      } else {  // rare overflow: true offsets + pairs from global
        int g0 = tp[idx], g1 = tp[idx + 1];
        if (g0 > TRI_CAP) g0 = TRI_CAP;
        if (g1 > TRI_CAP) g1 = TRI_CAP;
        for (int e = g0 + lane; e < g1; e += 64) {
          int2 ab = tri[e];
          st += dq[ab.x].x * dq[ab.y].x;
        }
      }
      red2(s2, st);
      float d0 = 1.f - dqi.x;
      float S1 = -eei.y + eei.x * d0;
      float S2 = s2 + dqi.y * d0;
      float sn = -dqi.y;
      double cross = 2.0 * (double)d0 * (double)sn + (double)st;
      double li = gamma - (ed + (double)S1) + (dAd + 2.0 * (double)S2 + cross);
      if (li <= loss && lane == 0) {
        svB[w] = make_float4(S1, S2, d0, eei.x);
        svCr[w] = cross;
        atomicOr(&maskL[b], 1u << w);
      }
    }
    __syncthreads();
    unsigned mask = maskL[b];
    if (mask == 0u) {
      pos = (total >= 16) ? nthpos(B, 15, pos) + 1 : pos + 1024;
      continue;
    }
    int k = __builtin_ctz(mask);
    int Pk = nthpos(B, k, pos);
    int idx = ordl[Pk];
    float4 A = svB[k];       // {S1, S2, d0, ei}
    double aCr = svCr[k];
    uint2 rt = rtP[idx];
    int r0 = rt.x & 0xffff, r1 = rt.y & 0xffff;
    ed += (double)A.x;
    dAd += 2.0 * (double)A.y + aCr;
    // phase 1: q/E scatter with OLD d (evals of this round already done)
    for (int e = r0 + w; e < r1; e += 16) {
      int a = colL[e];
      float da = -dq[a].x;
      if (da != 0.f) {
        float ea = ee[a].x;
        uint2 art = rtP[a];
        int b0 = art.x & 0xffff, b1 = art.y & 0xffff;
        for (int eb = b0 + lane; eb < b1; eb += 64) {
          int bb = colL[eb];
          atomicAdd(&dq[bb].y, da);
          atomicAdd(&ee[bb].y, ea * da);
        }
      }
    }
    for (int e = r0 + t; e < r1; e += 1024) {
      int bb = colL[e];
      atomicAdd(&dq[bb].y, A.z);
      atomicAdd(&ee[bb].y, A.w * A.z);
    }
    __syncthreads();
    // phase 2: d updates + decided/sel bits + mask reset
    if (t == 0) {
      dq[idx].x = 1.f;
      atomicOr(&decidedL[idx >> 5], 1u << (idx & 31));
      atomicOr(&selL[idx >> 5], 1u << (idx & 31));
      maskL[b] = 0u;
    }
    for (int e = r0 + t; e < r1; e += 1024) {
      int j = colL[e];
      dq[j].x = 0.f;
      atomicOr(&decidedL[j >> 5], 1u << (j & 31));
    }
    __syncthreads();
    pos = Pk + 1;
  }
  for (int i = t; i < NN; i += 1024)
    selb_g[i] = (u8)((selL[i >> 5] >> (i & 31)) & 1u);
}

// ---------------- boolean A^2 / A^3 ----------------
__global__ void k_reach(const u64* __restrict__ src, const int* __restrict__ rp,
                        const int* __restrict__ col, u64* __restrict__ dst) {
  int node = blockIdx.x * 2 + (threadIdx.x >> 5);
  int w = threadIdx.x & 31;
  u64 acc = 0;
  for (int e = rp[node]; e < rp[node + 1]; ++e) acc |= src[((size_t)col[e] << 5) + w];
  dst[((size_t)node << 5) + w] = acc;
}

// ---------------- outputs (fused) ----------------
__global__ void k_out(const u64* __restrict__ row2, const u64* __restrict__ row3,
                      const u8* __restrict__ selb, const float* __restrict__ x,
                      const int* __restrict__ batch, const double* __restrict__ scal,
                      float* __restrict__ o_x, float* __restrict__ o_adj,
                      float* __restrict__ o_sel, float* __restrict__ o_bat,
                      float* __restrict__ o_loss) {
  int idx = blockIdx.x * blockDim.x + threadIdx.x; // NN*NN
  {
    int i = idx >> 11, j = idx & 2047;
    int wo = (i << 5) + (j >> 6);
    u64 b = (row2[wo] | row3[wo]) >> (j & 63);
    o_adj[idx] = ((b & 1ull) && i != j && selb[i] && selb[j]) ? 1.f : 0.f;
  }
  if (idx < NN * DIMF) {
    int i = idx >> 8;
    o_x[idx] = selb[i] ? x[idx] : 0.f;
  }
  if (idx < NN) {
    o_sel[idx] = selb[idx] ? 1.f : 0.f;
    o_bat[idx] = selb[idx] ? (float)batch[idx] : -1.f;
  }
  if (idx == 0) o_loss[0] = (float)scal[3];
}

extern "C" void kernel_launch(void* const* d_in, const int* in_sizes, int n_in,
                              void* d_out, int out_size, void* d_ws, size_t ws_size,
                              hipStream_t stream) {
  const float* x    = (const float*)d_in[0];
  const int*   ei   = (const int*)d_in[1];
  const int*   batch= (const int*)d_in[2];
  const float* w11  = (const float*)d_in[3];
  const float* b11  = (const float*)d_in[4];
  const float* g1   = (const float*)d_in[5];
  const float* be1  = (const float*)d_in[6];
  const float* w12  = (const float*)d_in[7];
  const float* b12  = (const float*)d_in[8];
  const float* w21  = (const float*)d_in[9];
  const float* b21  = (const float*)d_in[10];
  const float* g2   = (const float*)d_in[11];
  const float* be2  = (const float*)d_in[12];
  const float* w22  = (const float*)d_in[13];
  const float* b22  = (const float*)d_in[14];
  const float* w31  = (const float*)d_in[15];
  const float* b31  = (const float*)d_in[16];
  const float* g3   = (const float*)d_in[17];
  const float* be3  = (const float*)d_in[18];
  const float* w32  = (const float*)d_in[19];
  const float* b32  = (const float*)d_in[20];

  char* wsb = (char*)d_ws;
  size_t cur = 0;
  auto alloc = [&](size_t bytes) -> void* {
    void* pp = wsb + cur;
    cur += (bytes + 255) & ~(size_t)255;
    return pp;
  };
  u64*    rowbits = (u64*)alloc((size_t)NN * W32 * 8);
  u64*    row2    = (u64*)alloc((size_t)NN * W32 * 8);
  u64*    row3    = (u64*)alloc((size_t)NN * W32 * 8);
  double* seggam  = (double*)alloc(NG * 8);
  double* scal    = (double*)alloc(4 * 8);
  int*    deg     = (int*)alloc(NN * 4);
  int*    rowptr  = (int*)alloc((NN + 1) * 4);
  int*    colx    = (int*)alloc(65536 * 4);
  int*    tricnt  = (int*)alloc(NN * 4);
  int*    triptr  = (int*)alloc((NN + 1) * 4);
  int2*   tri     = (int2*)alloc((size_t)TRI_CAP * 8);
  int*    segst   = (int*)alloc((NG + 1) * 4);
  float*  ent     = (float*)alloc(NN * 4);
  float*  V       = (float*)alloc(NN * 4);
  float*  p       = (float*)alloc(NN * 4);
  float*  agg1    = (float*)alloc(NN * 4);
  float*  scale   = (float*)alloc(HIDN * 4);
  float*  shift   = (float*)alloc(HIDN * 4);
  float*  tA      = (float*)alloc((size_t)NN * HIDN * 4);
  float*  tB      = (float*)alloc((size_t)NN * HIDN * 4);
  float*  tC      = (float*)alloc((size_t)NN * HIDN * 4);
  u8*     selb    = (u8*)alloc(NN);

  float* out    = (float*)d_out;
  float* o_x    = out;                       // 524288
  float* o_adj  = out + 524288;              // 4194304
  float* o_sel  = out + 4718592;             // 2048
  float* o_bat  = out + 4720640;             // 2048
  float* o_loss = out + 4722688;             // 1

  k_init<<<64, 256, 0, stream>>>(rowbits, segst);
  k_edges<<<128, 256, 0, stream>>>(ei, rowbits);
  k_deg<<<8, 256, 0, stream>>>(rowbits, deg, batch, segst);
  k_scan2048<<<1, 256, 0, stream>>>(deg, rowptr);
  k_extract<<<8, 256, 0, stream>>>(rowbits, rowptr, colx, tricnt);
  k_scan2048<<<1, 256, 0, stream>>>(tricnt, triptr);
  k_trifill<<<8, 256, 0, stream>>>(rowbits, rowptr, colx, triptr, tri);
  k_V<<<NN, 256, 0, stream>>>(x, rowptr, colx, V);
  k_soft<<<NG, 256, 0, stream>>>(V, segst, ent, seggam);

  // layer 1
  k_agg1<<<8, 256, 0, stream>>>(ent, rowptr, colx, agg1);
  k_lin1<<<1024, 256, 0, stream>>>(agg1, w11, b11, tA);
  k_bn<<<HIDN, 256, 0, stream>>>(tA, g1, be1, scale, shift);
  k_mm<1, 0><<<NN / 8, HIDN, 0, stream>>>(tA, w12, b12, scale, shift, tB);
  // layer 2
  k_agg128<<<NN, HIDN, 0, stream>>>(tB, rowptr, colx, tC);
  k_mm<0, 1><<<NN / 8, HIDN, 0, stream>>>(tC, w21, b21, scale, shift, tA);
  k_bn<<<HIDN, 256, 0, stream>>>(tA, g2, be2, scale, shift);
  k_mm<1, 0><<<NN / 8, HIDN, 0, stream>>>(tA, w22, b22, scale, shift, tB);
  // layer 3
  k_agg128<<<NN, HIDN, 0, stream>>>(tB, rowptr, colx, tC);
  k_mm<0, 1><<<NN / 8, HIDN, 0, stream>>>(tC, w31, b31, scale, shift, tA);
  k_bn<<<HIDN, 256, 0, stream>>>(tA, g3, be3, scale, shift);
  k_lin3<<<NN, HIDN, 0, stream>>>(tA, scale, shift, w32, b32, p);

  k_greedy<<<1, 1024, 0, stream>>>(rowptr, colx, triptr, tri, p, ent, seggam, scal, selb);

  k_reach<<<NN / 2, 64, 0, stream>>>(rowbits, rowptr, colx, row2);
  k_reach<<<NN / 2, 64, 0, stream>>>(row2, rowptr, colx, row3);
  k_out<<<NN * NN / 256, 256, 0, stream>>>(row2, row3, selb, x, batch, scal,
                                           o_x, o_adj, o_sel, o_bat, o_loss);

  (void)in_sizes; (void)n_in; (void)out_size; (void)ws_size;
}

// Round 7
// 1862.868 us; speedup vs baseline: 1.0440x; 1.0440x over previous
//
#include <hip/hip_runtime.h>
#include <hip/hip_cooperative_groups.h>
#include <math.h>

namespace cg = cooperative_groups;

#define NN 2048
#define DIMF 256
#define HIDN 128
#define NG 8
#define NEDGES 32768
#define W32 32
#define TRI_CAP 131072
#define TRI_LDS 4864
#define NB 64
#define NT 1024
#define GSZ (NB * NT)

typedef unsigned long long u64;
typedef unsigned char u8;
typedef unsigned short u16;

struct Params {
  const float* x; const int* ei; const int* batch;
  const float* w11; const float* b11; const float* g1; const float* be1;
  const float* w12; const float* b12;
  const float* w21; const float* b21; const float* g2; const float* be2;
  const float* w22; const float* b22;
  const float* w31; const float* b31; const float* g3; const float* be3;
  const float* w32; const float* b32;
  u64* rowbits; u64* row2; u64* row3;
  int* deg; int* rowptr; int* colx; int* tricnt; int* triptr; int2* tri;
  int* segst; float* V; float* ent; double* seggam; double* lossAB; double* scal;
  float* agg1; float* scaleS; float* shiftS;
  float* tA; float* tB; float* tC;
  float* p; float* q0; float* e0; int* order;
};

// ---- block-0 scan of 2048 ints (1024 threads) ----
__device__ void scan2048b(const int* in, int* out, int* part, int t) {
  int v0 = in[2 * t], v1 = in[2 * t + 1];
  int s = v0 + v1;
  part[t] = s;
  __syncthreads();
  for (int off = 1; off < 1024; off <<= 1) {
    int y = (t >= off) ? part[t - off] : 0;
    __syncthreads();
    part[t] += y;
    __syncthreads();
  }
  int run = part[t] - s;
  out[2 * t] = run; out[2 * t + 1] = run + v0;
  if (t == 1023) out[NN] = part[1023];
}

// ---- BN stats phase: 2 cols per block. mode0: t=relu(agg*w1+b1); mode1: t=src[i*128+c] ----
__device__ void bn_phase(int blk, int t, int mode, const float* aggv,
                         const float* w1, const float* b1, const float* src,
                         const float* g, const float* be,
                         float* scaleS, float* shiftS, double* bnP) {
  int c = 2 * blk + (t >> 9);
  int tid = t & 511;
  double s = 0.0, ss = 0.0;
  for (int r = 0; r < 4; ++r) {
    int i = tid + 512 * r;
    float v;
    if (mode == 0) { v = aggv[i] * w1[c] + b1[c]; v = v > 0.f ? v : 0.f; }
    else v = src[i * HIDN + c];
    s += (double)v; ss += (double)v * (double)v;
  }
  for (int off = 32; off; off >>= 1) { s += __shfl_down(s, off); ss += __shfl_down(ss, off); }
  int w = t >> 6;
  if ((t & 63) == 0) { bnP[2 * w] = s; bnP[2 * w + 1] = ss; }
  __syncthreads();
  if (t == 0 || t == 512) {
    int wb = (t >> 9) * 8;
    double S = 0.0, SS = 0.0;
    for (int k = 0; k < 8; ++k) { S += bnP[2 * (wb + k)]; SS += bnP[2 * (wb + k) + 1]; }
    double mu = S / NN;
    float var = (float)(SS / NN - mu * mu);
    float sc = g[c] / sqrtf(var + 1e-5f);
    scaleS[c] = sc;
    shiftS[c] = be[c] - (float)mu * sc;
  }
  __syncthreads();
}

// ---- mm phase: 32 rows/block; tile prep mode 0: relu(agg*w1+b1)*sc+sh; 1: src; 2: src*sc+sh ----
__device__ void mm_phase(int blk, int t, int mode, const float* aggv,
                         const float* w1, const float* b1, const float* src,
                         const float* scaleS, const float* shiftS,
                         const float* W, const float* bias, int relu, float* dst,
                         float* Wl, float* tile) {
  int r0 = blk * 32;
  for (int i = t; i < HIDN * HIDN; i += NT) Wl[i] = W[i];
  for (int i = t; i < 32 * HIDN; i += NT) {
    int r = i >> 7, k = i & 127;
    float v;
    if (mode == 0) { v = aggv[r0 + r] * w1[k] + b1[k]; v = v > 0.f ? v : 0.f; v = v * scaleS[k] + shiftS[k]; }
    else if (mode == 1) v = src[(r0 + r) * HIDN + k];
    else v = src[(r0 + r) * HIDN + k] * scaleS[k] + shiftS[k];
    tile[i] = v;
  }
  __syncthreads();
  int g = t >> 7;
  int c = t & 127;
  float a0 = 0.f, a1 = 0.f, a2 = 0.f, a3 = 0.f;
  for (int k = 0; k < HIDN; ++k) {
    float wv = Wl[k * HIDN + c];
    a0 += tile[g * HIDN + k] * wv;
    a1 += tile[(g + 8) * HIDN + k] * wv;
    a2 += tile[(g + 16) * HIDN + k] * wv;
    a3 += tile[(g + 24) * HIDN + k] * wv;
  }
  float bv = bias[c];
  a0 += bv; a1 += bv; a2 += bv; a3 += bv;
  if (relu) { a0 = fmaxf(a0, 0.f); a1 = fmaxf(a1, 0.f); a2 = fmaxf(a2, 0.f); a3 = fmaxf(a3, 0.f); }
  dst[(r0 + g) * HIDN + c] = a0;
  dst[(r0 + g + 8) * HIDN + c] = a1;
  dst[(r0 + g + 16) * HIDN + c] = a2;
  dst[(r0 + g + 24) * HIDN + c] = a3;
  __syncthreads();
}

// ---- softmax-entropy for one segment (1024 threads) ----
__device__ void soft_phase(int g, int t, const float* V, const int* segst,
                           float* ent, double* seggam, float* fmS, double* ddS) {
  int s = segst[g];
  int e = NN;
  for (int gg = g + 1; gg <= NG; ++gg) { int v = segst[gg]; if (v < e) e = v; }
  if (s >= e) { if (t == 0) seggam[g] = 0.0; return; }
  float m = -3.0e38f;
  for (int i = s + t; i < e; i += NT) m = fmaxf(m, V[i]);
  fmS[t] = m; __syncthreads();
  for (int off = 512; off; off >>= 1) { if (t < off) fmS[t] = fmaxf(fmS[t], fmS[t + off]); __syncthreads(); }
  float mx = fmS[0];
  __syncthreads();
  double sum = 0.0;
  for (int i = s + t; i < e; i += NT) sum += exp((double)V[i] - (double)mx);
  ddS[t] = sum; __syncthreads();
  for (int off = 512; off; off >>= 1) { if (t < off) ddS[t] += ddS[t + off]; __syncthreads(); }
  double tot = ddS[0];
  __syncthreads();
  double gs = 0.0;
  for (int i = s + t; i < e; i += NT) {
    double P = exp((double)V[i] - (double)mx) / tot;
    float ev = (P > 0.0) ? (float)(-P * log(P)) : 0.f;
    ent[i] = ev;
    gs += (double)ev;
  }
  ddS[t] = gs; __syncthreads();
  for (int off = 512; off; off >>= 1) { if (t < off) ddS[t] += ddS[t + off]; __syncthreads(); }
  if (t == 0) seggam[g] = ddS[0];
}

// =============== mega cooperative kernel (everything except greedy & out) ===============
__global__ void __launch_bounds__(1024, 1) mega(Params P) {
  cg::grid_group grid = cg::this_grid();
  int t = threadIdx.x, blk = blockIdx.x;
  int gtid = blk * NT + t;

  __shared__ double SMd[11776];  // 94208 B
  char* SM = (char*)SMd;
  float* Wl = (float*)SM;                 // 64 KB (mm)
  float* tile = (float*)(SM + 65536);     // 16 KB (mm)
  u64* skey = (u64*)SM;                   // 16 KB (sort, block 0)
  int* scanP = (int*)(SM + 81920);        // 4 KB
  float* fmS = (float*)(SM + 81920);      // 4 KB (soft)
  double* ddS = (double*)(SM + 86016);    // 8 KB (soft)
  double* bnP = (double*)(SM + 81920);    // 256 B (bn)

  // Ph0: zero
  for (int i = gtid; i < NN * W32; i += GSZ) P.rowbits[i] = 0ull;
  if (gtid <= NG) P.segst[gtid] = NN;
  if (gtid < 2) P.lossAB[gtid] = 0.0;
  grid.sync();
  // Ph1: edges
  for (int e = gtid; e < NEDGES; e += GSZ) {
    int u = P.ei[e], v = P.ei[NEDGES + e];
    atomicOr(&P.rowbits[((size_t)u << 5) + (v >> 6)], 1ull << (v & 63));
  }
  grid.sync();
  // Ph2: deg + segstart
  if (gtid < NN) {
    int c = 0;
    for (int w = 0; w < W32; ++w) c += __popcll(P.rowbits[(gtid << 5) + w]);
    P.deg[gtid] = c;
    if (gtid == 0 || P.batch[gtid] != P.batch[gtid - 1]) P.segst[P.batch[gtid]] = gtid;
  }
  grid.sync();
  // Ph3: scan deg -> rowptr
  if (blk == 0) scan2048b(P.deg, P.rowptr, scanP, t);
  grid.sync();
  // Ph4: extract CSR + triangle counts
  if (gtid < NN) {
    const u64* ri = P.rowbits + ((size_t)gtid << 5);
    int o = P.rowptr[gtid];
    for (int w = 0; w < W32; ++w) {
      u64 b = ri[w];
      while (b) { P.colx[o++] = (w << 6) + __builtin_ctzll(b); b &= b - 1; }
    }
    int c = 0;
    for (int e = P.rowptr[gtid]; e < o; ++e) {
      const u64* ra = P.rowbits + ((size_t)P.colx[e] << 5);
      for (int w = 0; w < W32; ++w) c += __popcll(ra[w] & ri[w]);
    }
    P.tricnt[gtid] = c;
  }
  grid.sync();
  // Ph5: scan tricnt -> triptr
  if (blk == 0) scan2048b(P.tricnt, P.triptr, scanP, t);
  grid.sync();
  // Ph6: trifill + row2 (A^2 reachability)
  if (gtid < NN) {
    const u64* ri = P.rowbits + ((size_t)gtid << 5);
    int o = P.triptr[gtid];
    for (int e = P.rowptr[gtid]; e < P.rowptr[gtid + 1]; ++e) {
      int a = P.colx[e];
      const u64* ra = P.rowbits + ((size_t)a << 5);
      for (int w = 0; w < W32; ++w) {
        u64 b = ra[w] & ri[w];
        while (b) {
          int j = (w << 6) + __builtin_ctzll(b);
          if (o < TRI_CAP) P.tri[o] = make_int2(a, j);
          ++o;
          b &= b - 1;
        }
      }
    }
  }
  for (int i2 = gtid; i2 < NN * W32; i2 += GSZ) {
    int node = i2 >> 5, w = i2 & 31;
    u64 acc = 0;
    for (int e = P.rowptr[node]; e < P.rowptr[node + 1]; ++e)
      acc |= P.rowbits[((size_t)P.colx[e] << 5) + w];
    P.row2[i2] = acc;
  }
  grid.sync();
  // Ph7: row3
  for (int i2 = gtid; i2 < NN * W32; i2 += GSZ) {
    int node = i2 >> 5, w = i2 & 31;
    u64 acc = 0;
    for (int e = P.rowptr[node]; e < P.rowptr[node + 1]; ++e)
      acc |= P.row2[((size_t)P.colx[e] << 5) + w];
    P.row3[i2] = acc;
  }
  grid.sync();
  // Ph8: V (32 lanes per node, 8 dims per lane)
  {
    int node = gtid >> 5, lane = gtid & 31;
    int r0 = P.rowptr[node], r1 = P.rowptr[node + 1];
    double acc = 0.0;
    for (int r = 0; r < 8; ++r) {
      int d = lane + 32 * r;
      float xi = P.x[node * DIMF + d];
      float s1 = 0.f, s2 = 0.f;
      for (int e = r0; e < r1; ++e) {
        float xj = P.x[P.colx[e] * DIMF + d];
        s1 += xj; s2 += xj * xj;
      }
      float dg = (float)(r1 - r0);
      float val = dg * xi * xi - 2.f * xi * s1 + s2;
      acc += (double)val * (double)val;
    }
    for (int m = 16; m; m >>= 1) acc += __shfl_xor(acc, m, 32);
    if (lane == 0) P.V[node] = (float)sqrt(acc);
  }
  grid.sync();
  // Ph9: per-graph softmax entropy
  if (blk < NG) soft_phase(blk, t, P.V, P.segst, P.ent, P.seggam, fmS, ddS);
  grid.sync();
  // Ph10: agg1 = ent + A@ent
  if (gtid < NN) {
    float a = P.ent[gtid];
    for (int e = P.rowptr[gtid]; e < P.rowptr[gtid + 1]; ++e) a += P.ent[P.colx[e]];
    P.agg1[gtid] = a;
  }
  grid.sync();
  // Ph11: bn1 stats from relu(agg1*w11+b11)
  bn_phase(blk, t, 0, P.agg1, P.w11, P.b11, (const float*)0, P.g1, P.be1, P.scaleS, P.shiftS, bnP);
  grid.sync();
  // Ph12: mm1 -> tB
  mm_phase(blk, t, 0, P.agg1, P.w11, P.b11, (const float*)0, P.scaleS, P.shiftS, P.w12, P.b12, 0, P.tB, Wl, tile);
  grid.sync();
  // Ph13: agg2 -> tC
  for (int idx = gtid; idx < NN * HIDN; idx += GSZ) {
    int i = idx >> 7, k = idx & 127;
    float a = P.tB[idx];
    for (int e = P.rowptr[i]; e < P.rowptr[i + 1]; ++e) a += P.tB[P.colx[e] * HIDN + k];
    P.tC[idx] = a;
  }
  grid.sync();
  // Ph14: mm2 -> tA = relu(tC@w21+b21)
  mm_phase(blk, t, 1, (const float*)0, (const float*)0, (const float*)0, P.tC, P.scaleS, P.shiftS, P.w21, P.b21, 1, P.tA, Wl, tile);
  grid.sync();
  // Ph15: bn2
  bn_phase(blk, t, 1, (const float*)0, (const float*)0, (const float*)0, P.tA, P.g2, P.be2, P.scaleS, P.shiftS, bnP);
  grid.sync();
  // Ph16: mm3 -> tB = (tA*sc+sh)@w22+b22
  mm_phase(blk, t, 2, (const float*)0, (const float*)0, (const float*)0, P.tA, P.scaleS, P.shiftS, P.w22, P.b22, 0, P.tB, Wl, tile);
  grid.sync();
  // Ph17: agg3 -> tC
  for (int idx = gtid; idx < NN * HIDN; idx += GSZ) {
    int i = idx >> 7, k = idx & 127;
    float a = P.tB[idx];
    for (int e = P.rowptr[i]; e < P.rowptr[i + 1]; ++e) a += P.tB[P.colx[e] * HIDN + k];
    P.tC[idx] = a;
  }
  grid.sync();
  // Ph18: mm4 -> tA = relu(tC@w31+b31)
  mm_phase(blk, t, 1, (const float*)0, (const float*)0, (const float*)0, P.tC, P.scaleS, P.shiftS, P.w31, P.b31, 1, P.tA, Wl, tile);
  grid.sync();
  // Ph19: bn3
  bn_phase(blk, t, 1, (const float*)0, (const float*)0, (const float*)0, P.tA, P.g3, P.be3, P.scaleS, P.shiftS, bnP);
  grid.sync();
  // Ph20: lin3 -> p
  {
    int node = gtid >> 5, lane = gtid & 31;
    float s = 0.f;
    for (int r = 0; r < 4; ++r) {
      int k = lane + 32 * r;
      s += (P.tA[node * HIDN + k] * P.scaleS[k] + P.shiftS[k]) * P.w32[k];
    }
    for (int m = 16; m; m >>= 1) s += __shfl_xor(s, m, 32);
    if (lane == 0) P.p[node] = 1.f / (1.f + expf(-(s + P.b32[0])));
  }
  grid.sync();
  // Ph21: block 0 sorts; other blocks compute q0/e0 + loss partials
  if (blk == 0) {
    for (int i2 = t; i2 < NN; i2 += NT) {
      unsigned bb = __float_as_uint(P.p[i2]);
      unsigned ss2 = (bb & 0x80000000u) ? ~bb : (bb | 0x80000000u);
      skey[i2] = ((u64)(~ss2) << 32) | (unsigned)i2;
    }
    __syncthreads();
    for (int k = 2; k <= NN; k <<= 1) {
      for (int j = k >> 1; j > 0; j >>= 1) {
        for (int i2 = t; i2 < NN; i2 += NT) {
          int ixj = i2 ^ j;
          if (ixj > i2) {
            bool up = ((i2 & k) == 0);
            u64 a = skey[i2], b2 = skey[ixj];
            if ((a > b2) == up) { skey[i2] = b2; skey[ixj] = a; }
          }
        }
        __syncthreads();
      }
    }
    P.order[t] = (int)(skey[t] & 0xFFFFFFFFull);
    P.order[t + 1024] = (int)(skey[t + 1024] & 0xFFFFFFFFull);
  } else {
    int i = gtid - NT;
    double la = 0.0, lb = 0.0;
    if (i < NN) {
      float qs = 0.f, es = 0.f;
      for (int e = P.rowptr[i]; e < P.rowptr[i + 1]; ++e) {
        int j = P.colx[e];
        float pj = P.p[j];
        qs += pj; es += P.ent[j] * pj;
      }
      P.q0[i] = qs; P.e0[i] = es;
      la = (double)P.ent[i] * (double)P.p[i];
      lb = (double)P.p[i] * (double)qs;
    }
    for (int off = 32; off; off >>= 1) { la += __shfl_down(la, off); lb += __shfl_down(lb, off); }
    if ((t & 63) == 0 && (la != 0.0 || lb != 0.0)) {
      atomicAdd(&P.lossAB[0], la);
      atomicAdd(&P.lossAB[1], lb);
    }
  }
  grid.sync();
  // Ph22: finalize scal
  if (gtid == 0) {
    double gamma = 0.0;
    for (int g = 0; g < NG; ++g) gamma += P.seggam[g];
    double A = P.lossAB[0], Bb = P.lossAB[1];
    P.scal[0] = gamma; P.scal[1] = A; P.scal[2] = Bb; P.scal[3] = gamma - A + Bb;
  }
}

// =============== greedy (round-5 proven version, verbatim) ===============
struct NodeF { float d, q, ent, pad; };

#define DPP2(ctrl)                                                                        \
  a += __int_as_float(__builtin_amdgcn_update_dpp(0, __float_as_int(a), ctrl, 0xf, 0xf, true)); \
  b += __int_as_float(__builtin_amdgcn_update_dpp(0, __float_as_int(b), ctrl, 0xf, 0xf, true));

__device__ __forceinline__ void red2(float& a, float& b) {
  DPP2(0x111)
  DPP2(0x112)
  DPP2(0x114)
  DPP2(0x118)
  DPP2(0x142)
  DPP2(0x143)
  a = __int_as_float(__builtin_amdgcn_readlane(__float_as_int(a), 63));
  b = __int_as_float(__builtin_amdgcn_readlane(__float_as_int(b), 63));
}

__global__ void __launch_bounds__(1024, 1) k_greedy(
    const int* __restrict__ rp, const int* __restrict__ col,
    const int* __restrict__ tp, const int2* __restrict__ tri,
    const int* __restrict__ order, const float* __restrict__ p,
    const float* __restrict__ ent, const float* __restrict__ q0,
    const float* __restrict__ e0, const double* __restrict__ scal,
    u8* __restrict__ selb_g) {
  __shared__ float2 dq[NN];
  __shared__ float2 ee[NN];
  __shared__ u16 colL[NEDGES];
  __shared__ u16 ordl[NN];
  __shared__ uint2 rtP[NN + 1];
  __shared__ ushort2 triL[TRI_LDS];
  __shared__ unsigned decidedL[64], selL[64];
  __shared__ unsigned maskL[2];
  __shared__ float4 svA[2][16];
  int t = threadIdx.x;
  int w = t >> 6, lane = t & 63;

  for (int i = t; i < NN; i += 1024) {
    dq[i] = make_float2(p[i], q0[i]);
    ee[i] = make_float2(ent[i], e0[i]);
    ordl[i] = (u16)order[i];
    int tv0 = tp[i]; if (tv0 > 65535) tv0 = 65535;
    int tv1 = tp[i + 1]; if (tv1 > 65535) tv1 = 65535;
    rtP[i] = make_uint2((unsigned)rp[i] | ((unsigned)tv0 << 16),
                        (unsigned)rp[i + 1] | ((unsigned)tv1 << 16));
  }
  for (int i = t; i < NEDGES; i += 1024) colL[i] = (u16)col[i];
  for (int i = t; i < TRI_LDS; i += 1024) {
    int2 ab = tri[i];
    triL[i] = make_ushort2((u16)(ab.x & 2047), (u16)(ab.y & 2047));
  }
  if (t < 64) { decidedL[t] = 0u; selL[t] = 0u; }
  if (t < 2) maskL[t] = 0u;
  double gamma = scal[0], loss = scal[3];
  double ed = scal[1], dAd = scal[2];
  __syncthreads();
  for (int i = t; i < NN; i += 1024) {
    if (((rtP[i].y & 0xffffu) - (rtP[i].x & 0xffffu)) == 0u) {
      atomicOr(&decidedL[i >> 5], 1u << (i & 31));
      atomicOr(&selL[i >> 5], 1u << (i & 31));
    }
  }
  __syncthreads();

  int pos = 0, rc = 0;
  while (pos < NN) {
    int b = rc & 1; ++rc;
    int step = pos + w;
    if (step < NN) {
      int idx = ordl[step];
      if (!((decidedL[idx >> 5] >> (idx & 31)) & 1u)) {
        uint2 rt = rtP[idx];
        int r0 = rt.x & 0xffff, r1 = rt.y & 0xffff;
        int t0 = rt.x >> 16, t1 = rt.y >> 16;
        float2 dqi = dq[idx];
        float2 eei = ee[idx];
        float s2 = 0.f, st = 0.f;
        for (int e = r0 + lane; e < r1; e += 64) {
          float2 v = dq[colL[e]];
          s2 -= v.y * v.x;
        }
        if (t1 <= TRI_LDS) {
          for (int e = t0 + lane; e < t1; e += 64) {
            ushort2 ab = triL[e];
            st += dq[ab.x].x * dq[ab.y].x;
          }
        } else {
          int g0 = tp[idx], g1 = tp[idx + 1];
          if (g0 > TRI_CAP) g0 = TRI_CAP;
          if (g1 > TRI_CAP) g1 = TRI_CAP;
          for (int e = g0 + lane; e < g1; e += 64) {
            int2 ab = tri[e];
            st += dq[ab.x].x * dq[ab.y].x;
          }
        }
        red2(s2, st);
        float d0 = 1.f - dqi.x;
        float S1 = -eei.y + eei.x * d0;
        float S2 = s2 + dqi.y * d0;
        float sn = -dqi.y;
        double cross = 2.0 * (double)d0 * (double)sn + (double)st;
        double li = gamma - (ed + (double)S1) + (dAd + 2.0 * (double)S2 + cross);
        if (li <= loss && lane == 0) {
          svA[b][w] = make_float4(S1, S2, d0, st);
          atomicOr(&maskL[b], 1u << w);
        }
      }
    }
    __syncthreads();
    unsigned mask = maskL[b];
    if (mask == 0u) { pos += 16; continue; }
    int k = __builtin_ctz(mask);
    int idx = ordl[pos + k];
    float4 A = svA[b][k];
    float2 dqi = dq[idx];
    uint2 rt = rtP[idx];
    int r0 = rt.x & 0xffff, r1 = rt.y & 0xffff;
    {
      double cross = 2.0 * (double)A.z * (double)(-dqi.y) + (double)A.w;
      ed += (double)A.x;
      dAd += 2.0 * (double)A.y + cross;
    }
    __syncthreads();
    if (t == 0) maskL[b] = 0u;
    for (int e = r0 + w; e < r1; e += 16) {
      int a = colL[e];
      float da = -dq[a].x;
      if (da != 0.f) {
        float ea = ee[a].x;
        uint2 art = rtP[a];
        int b0 = art.x & 0xffff, b1 = art.y & 0xffff;
        for (int eb = b0 + lane; eb < b1; eb += 64) {
          int bb = colL[eb];
          atomicAdd(&dq[bb].y, da);
          atomicAdd(&ee[bb].y, ea * da);
        }
      }
    }
    {
      float ei = ee[idx].x;
      for (int e = r0 + t; e < r1; e += 1024) {
        int bb = colL[e];
        atomicAdd(&dq[bb].y, A.z);
        atomicAdd(&ee[bb].y, ei * A.z);
      }
    }
    __syncthreads();
    if (t == 0) {
      dq[idx].x = 1.f;
      atomicOr(&decidedL[idx >> 5], 1u << (idx & 31));
      atomicOr(&selL[idx >> 5], 1u << (idx & 31));
    }
    for (int e = r0 + t; e < r1; e += 1024) {
      int j = colL[e];
      dq[j].x = 0.f;
      atomicOr(&decidedL[j >> 5], 1u << (j & 31));
    }
    __syncthreads();
    pos += pos + k + 1 - pos;  // pos = pos + k + 1
  }
  for (int i = t; i < NN; i += 1024)
    selb_g[i] = (u8)((selL[i >> 5] >> (i & 31)) & 1u);
}

// =============== fused outputs ===============
__global__ void k_out(const u64* __restrict__ row2, const u64* __restrict__ row3,
                      const u8* __restrict__ selb, const float* __restrict__ x,
                      const int* __restrict__ batch, const double* __restrict__ scal,
                      float* __restrict__ o_x, float* __restrict__ o_adj,
                      float* __restrict__ o_sel, float* __restrict__ o_bat,
                      float* __restrict__ o_loss) {
  int idx = blockIdx.x * blockDim.x + threadIdx.x;
  {
    int i = idx >> 11, j = idx & 2047;
    int wo = (i << 5) + (j >> 6);
    u64 b = (row2[wo] | row3[wo]) >> (j & 63);
    o_adj[idx] = ((b & 1ull) && i != j && selb[i] && selb[j]) ? 1.f : 0.f;
  }
  if (idx < NN * DIMF) {
    int i = idx >> 8;
    o_x[idx] = selb[i] ? x[idx] : 0.f;
  }
  if (idx < NN) {
    o_sel[idx] = selb[idx] ? 1.f : 0.f;
    o_bat[idx] = selb[idx] ? (float)batch[idx] : -1.f;
  }
  if (idx == 0) o_loss[0] = (float)scal[3];
}

extern "C" void kernel_launch(void* const* d_in, const int* in_sizes, int n_in,
                              void* d_out, int out_size, void* d_ws, size_t ws_size,
                              hipStream_t stream) {
  Params P;
  P.x    = (const float*)d_in[0];
  P.ei   = (const int*)d_in[1];
  P.batch= (const int*)d_in[2];
  P.w11  = (const float*)d_in[3];
  P.b11  = (const float*)d_in[4];
  P.g1   = (const float*)d_in[5];
  P.be1  = (const float*)d_in[6];
  P.w12  = (const float*)d_in[7];
  P.b12  = (const float*)d_in[8];
  P.w21  = (const float*)d_in[9];
  P.b21  = (const float*)d_in[10];
  P.g2   = (const float*)d_in[11];
  P.be2  = (const float*)d_in[12];
  P.w22  = (const float*)d_in[13];
  P.b22  = (const float*)d_in[14];
  P.w31  = (const float*)d_in[15];
  P.b31  = (const float*)d_in[16];
  P.g3   = (const float*)d_in[17];
  P.be3  = (const float*)d_in[18];
  P.w32  = (const float*)d_in[19];
  P.b32  = (const float*)d_in[20];

  char* wsb = (char*)d_ws;
  size_t cur = 0;
  auto alloc = [&](size_t bytes) -> void* {
    void* pp = wsb + cur;
    cur += (bytes + 255) & ~(size_t)255;
    return pp;
  };
  P.rowbits = (u64*)alloc((size_t)NN * W32 * 8);
  P.row2    = (u64*)alloc((size_t)NN * W32 * 8);
  P.row3    = (u64*)alloc((size_t)NN * W32 * 8);
  P.seggam  = (double*)alloc(NG * 8);
  P.lossAB  = (double*)alloc(2 * 8);
  P.scal    = (double*)alloc(4 * 8);
  P.deg     = (int*)alloc(NN * 4);
  P.rowptr  = (int*)alloc((NN + 1) * 4);
  P.colx    = (int*)alloc(65536 * 4);
  P.tricnt  = (int*)alloc(NN * 4);
  P.triptr  = (int*)alloc((NN + 1) * 4);
  P.tri     = (int2*)alloc((size_t)TRI_CAP * 8);
  P.segst   = (int*)alloc((NG + 1) * 4);
  P.order   = (int*)alloc(NN * 4);
  P.V       = (float*)alloc(NN * 4);
  P.ent     = (float*)alloc(NN * 4);
  P.p       = (float*)alloc(NN * 4);
  P.q0      = (float*)alloc(NN * 4);
  P.e0      = (float*)alloc(NN * 4);
  P.agg1    = (float*)alloc(NN * 4);
  P.scaleS  = (float*)alloc(HIDN * 4);
  P.shiftS  = (float*)alloc(HIDN * 4);
  P.tA      = (float*)alloc((size_t)NN * HIDN * 4);
  P.tB      = (float*)alloc((size_t)NN * HIDN * 4);
  P.tC      = (float*)alloc((size_t)NN * HIDN * 4);
  u8* selb  = (u8*)alloc(NN);

  float* out    = (float*)d_out;
  float* o_x    = out;
  float* o_adj  = out + 524288;
  float* o_sel  = out + 4718592;
  float* o_bat  = out + 4720640;
  float* o_loss = out + 4722688;

  void* args[] = { &P };
  hipLaunchCooperativeKernel((void*)mega, dim3(NB), dim3(NT), args, 0, stream);

  k_greedy<<<1, 1024, 0, stream>>>(P.rowptr, P.colx, P.triptr, P.tri, P.order,
                                   P.p, P.ent, P.q0, P.e0, P.scal, selb);

  k_out<<<NN * NN / 256, 256, 0, stream>>>(P.row2, P.row3, selb, P.x, P.batch, P.scal,
                                           o_x, o_adj, o_sel, o_bat, o_loss);

  (void)in_sizes; (void)n_in; (void)out_size; (void)ws_size;
}

// Round 8
// 1445.158 us; speedup vs baseline: 1.3458x; 1.2890x over previous
//
#include <hip/hip_runtime.h>
#include <hip/hip_cooperative_groups.h>
#include <math.h>

namespace cg = cooperative_groups;

#define NN 2048
#define DIMF 256
#define HIDN 128
#define NG 8
#define NEDGES 32768
#define W32 32
#define TRI_CAP 131072
#define TRI_LDS 4864
#define NB 256
#define NT 512
#define GSZ (NB * NT)

typedef unsigned long long u64;
typedef unsigned char u8;
typedef unsigned short u16;

struct Params {
  const float* x; const int* ei; const int* batch;
  const float* w11; const float* b11; const float* g1; const float* be1;
  const float* w12; const float* b12;
  const float* w21; const float* b21; const float* g2; const float* be2;
  const float* w22; const float* b22;
  const float* w31; const float* b31; const float* g3; const float* be3;
  const float* w32; const float* b32;
  u64* rowbits; u64* row2; u64* row3;
  int* deg; int* rowptr; int* colx; int* tricnt; int* triptr; int2* tri;
  int* segst; float* V; float* ent; double* seggam; double* lossAB; double* scal;
  float* agg1; float* scaleS; float* shiftS;
  float* tA; float* tB; float* tC;
  float* p; float* q0; float* e0; int* order;
};

// block-0 scan of 2048 ints with 512 threads
__device__ void scan2048b(const int* in, int* out, int* part, int t) {
  int v0 = in[4 * t], v1 = in[4 * t + 1], v2 = in[4 * t + 2], v3 = in[4 * t + 3];
  int s = v0 + v1 + v2 + v3;
  part[t] = s;
  __syncthreads();
  for (int off = 1; off < 512; off <<= 1) {
    int y = (t >= off) ? part[t - off] : 0;
    __syncthreads();
    part[t] += y;
    __syncthreads();
  }
  int run = part[t] - s;
  out[4 * t] = run; out[4 * t + 1] = run + v0;
  out[4 * t + 2] = run + v0 + v1; out[4 * t + 3] = run + v0 + v1 + v2;
  if (t == 511) out[NN] = part[511];
}

// BN stats: one column per block (blk < 128). mode0: v=relu(agg*w1+b1); mode1: v=src[i*128+c]
__device__ void bn_phase(int c, int t, int mode, const float* aggv,
                         const float* w1, const float* b1, const float* src,
                         const float* g, const float* be,
                         float* scaleS, float* shiftS, double* bnP) {
  double s = 0.0, ss = 0.0;
  for (int r = 0; r < 4; ++r) {
    int i = t + 512 * r;
    float v;
    if (mode == 0) { v = aggv[i] * w1[c] + b1[c]; v = v > 0.f ? v : 0.f; }
    else v = src[i * HIDN + c];
    s += (double)v; ss += (double)v * (double)v;
  }
  for (int off = 32; off; off >>= 1) { s += __shfl_down(s, off); ss += __shfl_down(ss, off); }
  if ((t & 63) == 0) { bnP[2 * (t >> 6)] = s; bnP[2 * (t >> 6) + 1] = ss; }
  __syncthreads();
  if (t == 0) {
    double S = 0.0, SS = 0.0;
    for (int k = 0; k < 8; ++k) { S += bnP[2 * k]; SS += bnP[2 * k + 1]; }
    double mu = S / NN;
    float var = (float)(SS / NN - mu * mu);
    float sc = g[c] / sqrtf(var + 1e-5f);
    scaleS[c] = sc;
    shiftS[c] = be[c] - (float)mu * sc;
  }
  __syncthreads();
}

// mm: 8 rows per block. tile mode 0: relu(agg*w1+b1)*sc+sh; 1: src; 2: src*sc+sh
__device__ void mm_phase(int blk, int t, int mode, const float* aggv,
                         const float* w1, const float* b1, const float* src,
                         const float* scaleS, const float* shiftS,
                         const float* W, const float* bias, int relu, float* dst,
                         float* Wl, float* tile) {
  int r0 = blk * 8;
  for (int i = t; i < HIDN * HIDN; i += NT) Wl[i] = W[i];
  for (int i = t; i < 8 * HIDN; i += NT) {
    int r = i >> 7, k = i & 127;
    float v;
    if (mode == 0) { v = aggv[r0 + r] * w1[k] + b1[k]; v = v > 0.f ? v : 0.f; v = v * scaleS[k] + shiftS[k]; }
    else if (mode == 1) v = src[(r0 + r) * HIDN + k];
    else v = src[(r0 + r) * HIDN + k] * scaleS[k] + shiftS[k];
    tile[i] = v;
  }
  __syncthreads();
  int g = t >> 7, c = t & 127;
  float a0 = 0.f, a1 = 0.f;
  for (int k = 0; k < HIDN; ++k) {
    float wv = Wl[k * HIDN + c];
    a0 += tile[g * HIDN + k] * wv;
    a1 += tile[(g + 4) * HIDN + k] * wv;
  }
  float bv = bias[c];
  a0 += bv; a1 += bv;
  if (relu) { a0 = fmaxf(a0, 0.f); a1 = fmaxf(a1, 0.f); }
  dst[(r0 + g) * HIDN + c] = a0;
  dst[(r0 + g + 4) * HIDN + c] = a1;
  __syncthreads();
}

// softmax-entropy for one segment (512 threads)
__device__ void soft_phase(int g, int t, const float* V, const int* segst,
                           float* ent, double* seggam, float* fmS, double* ddS) {
  int s = segst[g];
  int e = NN;
  for (int gg = g + 1; gg <= NG; ++gg) { int v = segst[gg]; if (v < e) e = v; }
  if (s >= e) { if (t == 0) seggam[g] = 0.0; return; }
  float m = -3.0e38f;
  for (int i = s + t; i < e; i += NT) m = fmaxf(m, V[i]);
  fmS[t] = m; __syncthreads();
  for (int off = 256; off; off >>= 1) { if (t < off) fmS[t] = fmaxf(fmS[t], fmS[t + off]); __syncthreads(); }
  float mx = fmS[0];
  __syncthreads();
  double sum = 0.0;
  for (int i = s + t; i < e; i += NT) sum += exp((double)V[i] - (double)mx);
  ddS[t] = sum; __syncthreads();
  for (int off = 256; off; off >>= 1) { if (t < off) ddS[t] += ddS[t + off]; __syncthreads(); }
  double tot = ddS[0];
  __syncthreads();
  double gs = 0.0;
  for (int i = s + t; i < e; i += NT) {
    double P = exp((double)V[i] - (double)mx) / tot;
    float ev = (P > 0.0) ? (float)(-P * log(P)) : 0.f;
    ent[i] = ev;
    gs += (double)ev;
  }
  ddS[t] = gs; __syncthreads();
  for (int off = 256; off; off >>= 1) { if (t < off) ddS[t] += ddS[t + off]; __syncthreads(); }
  if (t == 0) seggam[g] = ddS[0];
}

// =============== mega cooperative kernel ===============
__global__ void __launch_bounds__(NT, 1) mega(Params P) {
  cg::grid_group grid = cg::this_grid();
  int t = threadIdx.x, blk = blockIdx.x;
  int gtid = blk * NT + t;

  __shared__ double SMd[8704];  // 69632 B
  char* SM = (char*)SMd;
  float* Wl = (float*)SM;                 // 64 KB (mm)
  float* tile = (float*)(SM + 65536);     // 4 KB (mm)
  int* scanP = (int*)SM;                  // 2 KB (scan, block 0)
  float* fmS = (float*)SM;                // 2 KB (soft)
  double* ddS = (double*)(SM + 4096);     // 4 KB (soft)
  double* bnP = (double*)SM;              // 128 B (bn)

  // P0: zero
  for (int i = gtid; i < NN * W32; i += GSZ) P.rowbits[i] = 0ull;
  if (gtid <= NG) P.segst[gtid] = NN;
  if (gtid < 2) P.lossAB[gtid] = 0.0;
  grid.sync();
  // P1: edges
  for (int e = gtid; e < NEDGES; e += GSZ) {
    int u = P.ei[e], v = P.ei[NEDGES + e];
    atomicOr(&P.rowbits[((size_t)u << 5) + (v >> 6)], 1ull << (v & 63));
  }
  grid.sync();
  // P2: deg (32 lanes/node) + segstart
  {
    int node = gtid >> 5, lane = gtid & 31;
    if (node < NN) {
      int c = __popcll(P.rowbits[((size_t)node << 5) + lane]);
      for (int off = 16; off; off >>= 1) c += __shfl_down(c, off, 32);
      if (lane == 0) P.deg[node] = c;
    }
    if (gtid < NN) {
      if (gtid == 0 || P.batch[gtid] != P.batch[gtid - 1]) P.segst[P.batch[gtid]] = gtid;
    }
  }
  grid.sync();
  // P3: scan deg -> rowptr
  if (blk == 0) scan2048b(P.deg, P.rowptr, scanP, t);
  grid.sync();
  // P4: extract CSR (wave-parallel) + tricnt
  {
    int node = gtid >> 5, lane = gtid & 31;
    u64 myword = 0; int r0 = 0, r1 = 0;
    if (node < NN) {
      myword = P.rowbits[((size_t)node << 5) + lane];
      int cnt = __popcll(myword);
      int incl = cnt;
      for (int off = 1; off < 32; off <<= 1) { int v = __shfl_up(incl, off, 32); if (lane >= off) incl += v; }
      r0 = P.rowptr[node]; r1 = P.rowptr[node + 1];
      int base = r0 + incl - cnt;
      u64 b = myword;
      while (b) { P.colx[base++] = (lane << 6) + (int)__builtin_ctzll(b); b &= b - 1; }
    }
    __syncthreads();  // colx of this node written by this block's lanes
    if (node < NN) {
      int c = 0;
      for (int e = r0; e < r1; ++e) {
        int a = P.colx[e];
        c += __popcll(P.rowbits[((size_t)a << 5) + lane] & myword);
      }
      for (int off = 16; off; off >>= 1) c += __shfl_down(c, off, 32);
      if (lane == 0) P.tricnt[node] = c;
    }
  }
  grid.sync();
  // P5: scan tricnt -> triptr
  if (blk == 0) scan2048b(P.tricnt, P.triptr, scanP, t);
  grid.sync();
  // P6: trifill (wave-parallel) + row2
  {
    int node = gtid >> 5, lane = gtid & 31;
    if (node < NN) {
      u64 myword = P.rowbits[((size_t)node << 5) + lane];
      int r0 = P.rowptr[node], r1 = P.rowptr[node + 1];
      int obase = P.triptr[node];
      for (int e = r0; e < r1; ++e) {
        int a = P.colx[e];
        u64 m = P.rowbits[((size_t)a << 5) + lane] & myword;
        int cnt = __popcll(m);
        int incl = cnt;
        for (int off = 1; off < 32; off <<= 1) { int v = __shfl_up(incl, off, 32); if (lane >= off) incl += v; }
        int o = obase + incl - cnt;
        u64 b = m;
        while (b) {
          int j = (lane << 6) + (int)__builtin_ctzll(b);
          if (o < TRI_CAP) P.tri[o] = make_int2(a, j);
          ++o; b &= b - 1;
        }
        obase += __shfl(incl, 31, 32);
      }
      // row2 for (node, word=lane)
      u64 acc = 0;
      for (int e = r0; e < r1; ++e)
        acc |= P.rowbits[((size_t)P.colx[e] << 5) + lane];
      P.row2[((size_t)node << 5) + lane] = acc;
    }
  }
  grid.sync();
  // P7: row3 + V (64 lanes/node)
  {
    if (gtid < NN * W32) {
      int nd = gtid >> 5, w = gtid & 31;
      u64 acc = 0;
      for (int e = P.rowptr[nd]; e < P.rowptr[nd + 1]; ++e)
        acc |= P.row2[((size_t)P.colx[e] << 5) + w];
      P.row3[gtid] = acc;
    }
    int node = gtid >> 6, lane = gtid & 63;
    int r0 = P.rowptr[node], r1 = P.rowptr[node + 1];
    double acc = 0.0;
    for (int r = 0; r < 4; ++r) {
      int d = lane + 64 * r;
      float xi = P.x[node * DIMF + d];
      float s1 = 0.f, s2 = 0.f;
      for (int e = r0; e < r1; ++e) {
        float xj = P.x[P.colx[e] * DIMF + d];
        s1 += xj; s2 += xj * xj;
      }
      float dg = (float)(r1 - r0);
      float val = dg * xi * xi - 2.f * xi * s1 + s2;
      acc += (double)val * (double)val;
    }
    for (int m = 32; m; m >>= 1) acc += __shfl_xor(acc, m);
    if (lane == 0) P.V[node] = (float)sqrt(acc);
  }
  grid.sync();
  // P8: softmax entropy per graph
  if (blk < NG) soft_phase(blk, t, P.V, P.segst, P.ent, P.seggam, fmS, ddS);
  grid.sync();
  // P9: agg1
  if (gtid < NN) {
    float a = P.ent[gtid];
    for (int e = P.rowptr[gtid]; e < P.rowptr[gtid + 1]; ++e) a += P.ent[P.colx[e]];
    P.agg1[gtid] = a;
  }
  grid.sync();
  // P10: bn1
  if (blk < HIDN) bn_phase(blk, t, 0, P.agg1, P.w11, P.b11, (const float*)0, P.g1, P.be1, P.scaleS, P.shiftS, bnP);
  grid.sync();
  // P11: mm1 -> tB
  mm_phase(blk, t, 0, P.agg1, P.w11, P.b11, (const float*)0, P.scaleS, P.shiftS, P.w12, P.b12, 0, P.tB, Wl, tile);
  grid.sync();
  // P12: agg2 tB -> tC
  for (int idx = gtid; idx < NN * HIDN; idx += GSZ) {
    int i = idx >> 7, k = idx & 127;
    float a = P.tB[idx];
    for (int e = P.rowptr[i]; e < P.rowptr[i + 1]; ++e) a += P.tB[P.colx[e] * HIDN + k];
    P.tC[idx] = a;
  }
  grid.sync();
  // P13: mm2 tC -> tA (relu)
  mm_phase(blk, t, 1, (const float*)0, (const float*)0, (const float*)0, P.tC, P.scaleS, P.shiftS, P.w21, P.b21, 1, P.tA, Wl, tile);
  grid.sync();
  // P14: bn2
  if (blk < HIDN) bn_phase(blk, t, 1, (const float*)0, (const float*)0, (const float*)0, P.tA, P.g2, P.be2, P.scaleS, P.shiftS, bnP);
  grid.sync();
  // P15: mm3 tA -> tB
  mm_phase(blk, t, 2, (const float*)0, (const float*)0, (const float*)0, P.tA, P.scaleS, P.shiftS, P.w22, P.b22, 0, P.tB, Wl, tile);
  grid.sync();
  // P16: agg3 tB -> tC
  for (int idx = gtid; idx < NN * HIDN; idx += GSZ) {
    int i = idx >> 7, k = idx & 127;
    float a = P.tB[idx];
    for (int e = P.rowptr[i]; e < P.rowptr[i + 1]; ++e) a += P.tB[P.colx[e] * HIDN + k];
    P.tC[idx] = a;
  }
  grid.sync();
  // P17: mm4 tC -> tA (relu)
  mm_phase(blk, t, 1, (const float*)0, (const float*)0, (const float*)0, P.tC, P.scaleS, P.shiftS, P.w31, P.b31, 1, P.tA, Wl, tile);
  grid.sync();
  // P18: bn3
  if (blk < HIDN) bn_phase(blk, t, 1, (const float*)0, (const float*)0, (const float*)0, P.tA, P.g3, P.be3, P.scaleS, P.shiftS, bnP);
  grid.sync();
  // P19: lin3 -> p (64 lanes/node)
  {
    int node = gtid >> 6, lane = gtid & 63;
    float s = 0.f;
    for (int r = 0; r < 2; ++r) {
      int k = lane + 64 * r;
      s += (P.tA[node * HIDN + k] * P.scaleS[k] + P.shiftS[k]) * P.w32[k];
    }
    for (int m = 32; m; m >>= 1) s += __shfl_xor(s, m);
    if (lane == 0) P.p[node] = 1.f / (1.f + expf(-(s + P.b32[0])));
  }
  grid.sync();
  // P20: q0/e0 + loss partials
  {
    double la = 0.0, lb = 0.0;
    if (gtid < NN) {
      int i = gtid;
      float qs = 0.f, es = 0.f;
      for (int e = P.rowptr[i]; e < P.rowptr[i + 1]; ++e) {
        int j = P.colx[e];
        float pj = P.p[j];
        qs += pj; es += P.ent[j] * pj;
      }
      P.q0[i] = qs; P.e0[i] = es;
      la = (double)P.ent[i] * (double)P.p[i];
      lb = (double)P.p[i] * (double)qs;
    }
    for (int off = 32; off; off >>= 1) { la += __shfl_down(la, off); lb += __shfl_down(lb, off); }
    if ((t & 63) == 0 && (la != 0.0 || lb != 0.0)) {
      atomicAdd(&P.lossAB[0], la);
      atomicAdd(&P.lossAB[1], lb);
    }
  }
}

// =============== k_fin: sort (1 block) + scal finalize ===============
__global__ void __launch_bounds__(1024, 1) k_fin(const float* __restrict__ p,
                                                 const double* __restrict__ seggam,
                                                 const double* __restrict__ lossAB,
                                                 double* __restrict__ scal,
                                                 int* __restrict__ order) {
  __shared__ u64 skey[NN];
  int t = threadIdx.x;
  for (int i = t; i < NN; i += 1024) {
    unsigned bb = __float_as_uint(p[i]);
    unsigned ss = (bb & 0x80000000u) ? ~bb : (bb | 0x80000000u);
    skey[i] = ((u64)(~ss) << 32) | (unsigned)i;
  }
  __syncthreads();
  for (int k = 2; k <= NN; k <<= 1) {
    for (int j = k >> 1; j > 0; j >>= 1) {
      for (int i = t; i < NN; i += 1024) {
        int ixj = i ^ j;
        if (ixj > i) {
          bool up = ((i & k) == 0);
          u64 a = skey[i], b = skey[ixj];
          if ((a > b) == up) { skey[i] = b; skey[ixj] = a; }
        }
      }
      __syncthreads();
    }
  }
  order[t] = (int)(skey[t] & 0xFFFFFFFFull);
  order[t + 1024] = (int)(skey[t + 1024] & 0xFFFFFFFFull);
  if (t == 0) {
    double gamma = 0.0;
    for (int g = 0; g < NG; ++g) gamma += seggam[g];
    double A = lossAB[0], Bb = lossAB[1];
    scal[0] = gamma; scal[1] = A; scal[2] = Bb; scal[3] = gamma - A + Bb;
  }
}

// =============== greedy (round-5 proven version) ===============
#define DPP2(ctrl)                                                                        \
  a += __int_as_float(__builtin_amdgcn_update_dpp(0, __float_as_int(a), ctrl, 0xf, 0xf, true)); \
  b += __int_as_float(__builtin_amdgcn_update_dpp(0, __float_as_int(b), ctrl, 0xf, 0xf, true));

__device__ __forceinline__ void red2(float& a, float& b) {
  DPP2(0x111)
  DPP2(0x112)
  DPP2(0x114)
  DPP2(0x118)
  DPP2(0x142)
  DPP2(0x143)
  a = __int_as_float(__builtin_amdgcn_readlane(__float_as_int(a), 63));
  b = __int_as_float(__builtin_amdgcn_readlane(__float_as_int(b), 63));
}

__global__ void __launch_bounds__(1024, 1) k_greedy(
    const int* __restrict__ rp, const int* __restrict__ col,
    const int* __restrict__ tp, const int2* __restrict__ tri,
    const int* __restrict__ order, const float* __restrict__ p,
    const float* __restrict__ ent, const float* __restrict__ q0,
    const float* __restrict__ e0, const double* __restrict__ scal,
    u8* __restrict__ selb_g) {
  __shared__ float2 dq[NN];
  __shared__ float2 ee[NN];
  __shared__ u16 colL[NEDGES];
  __shared__ u16 ordl[NN];
  __shared__ uint2 rtP[NN + 1];
  __shared__ ushort2 triL[TRI_LDS];
  __shared__ unsigned decidedL[64], selL[64];
  __shared__ unsigned maskL[2];
  __shared__ float4 svA[2][16];
  int t = threadIdx.x;
  int w = t >> 6, lane = t & 63;

  for (int i = t; i < NN; i += 1024) {
    dq[i] = make_float2(p[i], q0[i]);
    ee[i] = make_float2(ent[i], e0[i]);
    ordl[i] = (u16)order[i];
    int tv0 = tp[i]; if (tv0 > 65535) tv0 = 65535;
    int tv1 = tp[i + 1]; if (tv1 > 65535) tv1 = 65535;
    rtP[i] = make_uint2((unsigned)rp[i] | ((unsigned)tv0 << 16),
                        (unsigned)rp[i + 1] | ((unsigned)tv1 << 16));
  }
  for (int i = t; i < NEDGES; i += 1024) colL[i] = (u16)col[i];
  for (int i = t; i < TRI_LDS; i += 1024) {
    int2 ab = tri[i];
    triL[i] = make_ushort2((u16)(ab.x & 2047), (u16)(ab.y & 2047));
  }
  if (t < 64) { decidedL[t] = 0u; selL[t] = 0u; }
  if (t < 2) maskL[t] = 0u;
  double gamma = scal[0], loss = scal[3];
  double ed = scal[1], dAd = scal[2];
  __syncthreads();
  for (int i = t; i < NN; i += 1024) {
    if (((rtP[i].y & 0xffffu) - (rtP[i].x & 0xffffu)) == 0u) {
      atomicOr(&decidedL[i >> 5], 1u << (i & 31));
      atomicOr(&selL[i >> 5], 1u << (i & 31));
    }
  }
  __syncthreads();

  int pos = 0, rc = 0;
  while (pos < NN) {
    int b = rc & 1; ++rc;
    int step = pos + w;
    if (step < NN) {
      int idx = ordl[step];
      if (!((decidedL[idx >> 5] >> (idx & 31)) & 1u)) {
        uint2 rt = rtP[idx];
        int r0 = rt.x & 0xffff, r1 = rt.y & 0xffff;
        int t0 = rt.x >> 16, t1 = rt.y >> 16;
        float2 dqi = dq[idx];
        float2 eei = ee[idx];
        float s2 = 0.f, st = 0.f;
        for (int e = r0 + lane; e < r1; e += 64) {
          float2 v = dq[colL[e]];
          s2 -= v.y * v.x;
        }
        if (t1 <= TRI_LDS) {
          for (int e = t0 + lane; e < t1; e += 64) {
            ushort2 ab = triL[e];
            st += dq[ab.x].x * dq[ab.y].x;
          }
        } else {
          int g0 = tp[idx], g1 = tp[idx + 1];
          if (g0 > TRI_CAP) g0 = TRI_CAP;
          if (g1 > TRI_CAP) g1 = TRI_CAP;
          for (int e = g0 + lane; e < g1; e += 64) {
            int2 ab = tri[e];
            st += dq[ab.x].x * dq[ab.y].x;
          }
        }
        red2(s2, st);
        float d0 = 1.f - dqi.x;
        float S1 = -eei.y + eei.x * d0;
        float S2 = s2 + dqi.y * d0;
        float sn = -dqi.y;
        double cross = 2.0 * (double)d0 * (double)sn + (double)st;
        double li = gamma - (ed + (double)S1) + (dAd + 2.0 * (double)S2 + cross);
        if (li <= loss && lane == 0) {
          svA[b][w] = make_float4(S1, S2, d0, st);
          atomicOr(&maskL[b], 1u << w);
        }
      }
    }
    __syncthreads();
    unsigned mask = maskL[b];
    if (mask == 0u) { pos += 16; continue; }
    int k = __builtin_ctz(mask);
    int idx = ordl[pos + k];
    float4 A = svA[b][k];
    float2 dqi = dq[idx];
    uint2 rt = rtP[idx];
    int r0 = rt.x & 0xffff, r1 = rt.y & 0xffff;
    {
      double cross = 2.0 * (double)A.z * (double)(-dqi.y) + (double)A.w;
      ed += (double)A.x;
      dAd += 2.0 * (double)A.y + cross;
    }
    __syncthreads();
    if (t == 0) maskL[b] = 0u;
    for (int e = r0 + w; e < r1; e += 16) {
      int a = colL[e];
      float da = -dq[a].x;
      if (da != 0.f) {
        float ea = ee[a].x;
        uint2 art = rtP[a];
        int b0 = art.x & 0xffff, b1 = art.y & 0xffff;
        for (int eb = b0 + lane; eb < b1; eb += 64) {
          int bb = colL[eb];
          atomicAdd(&dq[bb].y, da);
          atomicAdd(&ee[bb].y, ea * da);
        }
      }
    }
    {
      float ei = ee[idx].x;
      for (int e = r0 + t; e < r1; e += 1024) {
        int bb = colL[e];
        atomicAdd(&dq[bb].y, A.z);
        atomicAdd(&ee[bb].y, ei * A.z);
      }
    }
    __syncthreads();
    if (t == 0) {
      dq[idx].x = 1.f;
      atomicOr(&decidedL[idx >> 5], 1u << (idx & 31));
      atomicOr(&selL[idx >> 5], 1u << (idx & 31));
    }
    for (int e = r0 + t; e < r1; e += 1024) {
      int j = colL[e];
      dq[j].x = 0.f;
      atomicOr(&decidedL[j >> 5], 1u << (j & 31));
    }
    __syncthreads();
    pos = pos + k + 1;
  }
  for (int i = t; i < NN; i += 1024)
    selb_g[i] = (u8)((selL[i >> 5] >> (i & 31)) & 1u);
}

// =============== fused outputs ===============
__global__ void k_out(const u64* __restrict__ row2, const u64* __restrict__ row3,
                      const u8* __restrict__ selb, const float* __restrict__ x,
                      const int* __restrict__ batch, const double* __restrict__ scal,
                      float* __restrict__ o_x, float* __restrict__ o_adj,
                      float* __restrict__ o_sel, float* __restrict__ o_bat,
                      float* __restrict__ o_loss) {
  int idx = blockIdx.x * blockDim.x + threadIdx.x;
  {
    int i = idx >> 11, j = idx & 2047;
    int wo = (i << 5) + (j >> 6);
    u64 b = (row2[wo] | row3[wo]) >> (j & 63);
    o_adj[idx] = ((b & 1ull) && i != j && selb[i] && selb[j]) ? 1.f : 0.f;
  }
  if (idx < NN * DIMF) {
    int i = idx >> 8;
    o_x[idx] = selb[i] ? x[idx] : 0.f;
  }
  if (idx < NN) {
    o_sel[idx] = selb[idx] ? 1.f : 0.f;
    o_bat[idx] = selb[idx] ? (float)batch[idx] : -1.f;
  }
  if (idx == 0) o_loss[0] = (float)scal[3];
}

extern "C" void kernel_launch(void* const* d_in, const int* in_sizes, int n_in,
                              void* d_out, int out_size, void* d_ws, size_t ws_size,
                              hipStream_t stream) {
  Params P;
  P.x    = (const float*)d_in[0];
  P.ei   = (const int*)d_in[1];
  P.batch= (const int*)d_in[2];
  P.w11  = (const float*)d_in[3];
  P.b11  = (const float*)d_in[4];
  P.g1   = (const float*)d_in[5];
  P.be1  = (const float*)d_in[6];
  P.w12  = (const float*)d_in[7];
  P.b12  = (const float*)d_in[8];
  P.w21  = (const float*)d_in[9];
  P.b21  = (const float*)d_in[10];
  P.g2   = (const float*)d_in[11];
  P.be2  = (const float*)d_in[12];
  P.w22  = (const float*)d_in[13];
  P.b22  = (const float*)d_in[14];
  P.w31  = (const float*)d_in[15];
  P.b31  = (const float*)d_in[16];
  P.g3   = (const float*)d_in[17];
  P.be3  = (const float*)d_in[18];
  P.w32  = (const float*)d_in[19];
  P.b32  = (const float*)d_in[20];

  char* wsb = (char*)d_ws;
  size_t cur = 0;
  auto alloc = [&](size_t bytes) -> void* {
    void* pp = wsb + cur;
    cur += (bytes + 255) & ~(size_t)255;
    return pp;
  };
  P.rowbits = (u64*)alloc((size_t)NN * W32 * 8);
  P.row2    = (u64*)alloc((size_t)NN * W32 * 8);
  P.row3    = (u64*)alloc((size_t)NN * W32 * 8);
  P.seggam  = (double*)alloc(NG * 8);
  P.lossAB  = (double*)alloc(2 * 8);
  P.scal    = (double*)alloc(4 * 8);
  P.deg     = (int*)alloc(NN * 4);
  P.rowptr  = (int*)alloc((NN + 1) * 4);
  P.colx    = (int*)alloc(65536 * 4);
  P.tricnt  = (int*)alloc(NN * 4);
  P.triptr  = (int*)alloc((NN + 1) * 4);
  P.tri     = (int2*)alloc((size_t)TRI_CAP * 8);
  P.segst   = (int*)alloc((NG + 1) * 4);
  P.order   = (int*)alloc(NN * 4);
  P.V       = (float*)alloc(NN * 4);
  P.ent     = (float*)alloc(NN * 4);
  P.p       = (float*)alloc(NN * 4);
  P.q0      = (float*)alloc(NN * 4);
  P.e0      = (float*)alloc(NN * 4);
  P.agg1    = (float*)alloc(NN * 4);
  P.scaleS  = (float*)alloc(HIDN * 4);
  P.shiftS  = (float*)alloc(HIDN * 4);
  P.tA      = (float*)alloc((size_t)NN * HIDN * 4);
  P.tB      = (float*)alloc((size_t)NN * HIDN * 4);
  P.tC      = (float*)alloc((size_t)NN * HIDN * 4);
  u8* selb  = (u8*)alloc(NN);

  float* out    = (float*)d_out;
  float* o_x    = out;
  float* o_adj  = out + 524288;
  float* o_sel  = out + 4718592;
  float* o_bat  = out + 4720640;
  float* o_loss = out + 4722688;

  void* args[] = { &P };
  hipLaunchCooperativeKernel((void*)mega, dim3(NB), dim3(NT), args, 0, stream);

  k_fin<<<1, 1024, 0, stream>>>(P.p, P.seggam, P.lossAB, P.scal, P.order);

  k_greedy<<<1, 1024, 0, stream>>>(P.rowptr, P.colx, P.triptr, P.tri, P.order,
                                   P.p, P.ent, P.q0, P.e0, P.scal, selb);

  k_out<<<NN * NN / 256, 256, 0, stream>>>(P.row2, P.row3, selb, P.x, P.batch, P.scal,
                                           o_x, o_adj, o_sel, o_bat, o_loss);

  (void)in_sizes; (void)n_in; (void)out_size; (void)ws_size;
}

// Round 9
// 1373.919 us; speedup vs baseline: 1.4156x; 1.0519x over previous
//
#include <hip/hip_runtime.h>
#include <math.h>

#define NN 2048
#define DIMF 256
#define HIDN 128
#define NG 8
#define NEDGES 32768
#define W32 32
#define TRI_CAP 131072
#define TRI_LDS 4864

typedef unsigned long long u64;
typedef unsigned char u8;
typedef unsigned short u16;

// ---------------- build adjacency ----------------
__global__ void k_init(u64* __restrict__ rowbits, int* __restrict__ segstart) {
  int i = blockIdx.x * blockDim.x + threadIdx.x;
  for (int k = i; k < NN * W32; k += gridDim.x * blockDim.x) rowbits[k] = 0ull;
  if (i <= NG) segstart[i] = NN;
}

__global__ void k_edges(const int* __restrict__ ei, u64* __restrict__ rowbits) {
  int e = blockIdx.x * blockDim.x + threadIdx.x;
  if (e >= NEDGES) return;
  int u = ei[e], v = ei[NEDGES + e];
  atomicOr(&rowbits[((size_t)u << 5) + (v >> 6)], 1ull << (v & 63));
}

// deg + segment bounds (fused)
__global__ void k_deg(const u64* __restrict__ rowbits, int* __restrict__ deg,
                      const int* __restrict__ batch, int* __restrict__ segstart) {
  int i = blockIdx.x * blockDim.x + threadIdx.x;
  if (i >= NN) return;
  int c = 0;
  for (int w = 0; w < W32; ++w) c += __popcll(rowbits[(i << 5) + w]);
  deg[i] = c;
  if (i == 0 || batch[i] != batch[i - 1]) segstart[batch[i]] = i;
}

// exclusive scan of 2048 ints -> out[0..2048]
__global__ void k_scan2048(const int* __restrict__ in, int* __restrict__ out) {
  __shared__ int part[256];
  int t = threadIdx.x;
  int v[8]; int s = 0;
  for (int k = 0; k < 8; ++k) { v[k] = in[t * 8 + k]; s += v[k]; }
  part[t] = s;
  __syncthreads();
  for (int off = 1; off < 256; off <<= 1) {
    int y = (t >= off) ? part[t - off] : 0;
    __syncthreads();
    part[t] += y;
    __syncthreads();
  }
  int run = part[t] - s;
  for (int k = 0; k < 8; ++k) { out[t * 8 + k] = run; run += v[k]; }
  if (t == 255) out[NN] = part[255];
}

// extract CSR + count triangle pairs (fused)
__global__ void k_extract(const u64* __restrict__ rowbits, const int* __restrict__ rp,
                          int* __restrict__ col, int* __restrict__ cnt) {
  int i = blockIdx.x * blockDim.x + threadIdx.x;
  if (i >= NN) return;
  const u64* ri = rowbits + ((size_t)i << 5);
  int o = rp[i];
  for (int w = 0; w < W32; ++w) {
    u64 b = ri[w];
    while (b) { col[o++] = (w << 6) + __builtin_ctzll(b); b &= b - 1; }
  }
  int c = 0;
  for (int e = rp[i]; e < o; ++e) {
    const u64* ra = rowbits + ((size_t)col[e] << 5);
    for (int w = 0; w < W32; ++w) c += __popcll(ra[w] & ri[w]);
  }
  cnt[i] = c;
}

__global__ void k_trifill(const u64* __restrict__ rowbits, const int* __restrict__ rp,
                          const int* __restrict__ col, const int* __restrict__ tp,
                          int2* __restrict__ tri) {
  int i = blockIdx.x * blockDim.x + threadIdx.x;
  if (i >= NN) return;
  const u64* ri = rowbits + ((size_t)i << 5);
  int o = tp[i];
  for (int e = rp[i]; e < rp[i + 1]; ++e) {
    int a = col[e];
    const u64* ra = rowbits + ((size_t)a << 5);
    for (int w = 0; w < W32; ++w) {
      u64 b = ra[w] & ri[w];
      while (b) {
        int j = (w << 6) + __builtin_ctzll(b);
        if (o < TRI_CAP) tri[o] = make_int2(a, j);
        ++o;
        b &= b - 1;
      }
    }
  }
}

// ---------------- entropy term ----------------
__global__ void k_V(const float* __restrict__ x, const int* __restrict__ rp,
                    const int* __restrict__ col, float* __restrict__ V) {
  int i = blockIdx.x; int t = threadIdx.x; // 256 threads = dims
  float xi = x[i * DIMF + t];
  float s1 = 0.f, s2 = 0.f;
  int r0 = rp[i], r1 = rp[i + 1];
  for (int e = r0; e < r1; ++e) {
    float xj = x[col[e] * DIMF + t];
    s1 += xj; s2 += xj * xj;
  }
  float dg = (float)(r1 - r0);
  float val = dg * xi * xi - 2.f * xi * s1 + s2;
  __shared__ double red[DIMF];
  red[t] = (double)val * (double)val;
  __syncthreads();
  for (int off = DIMF / 2; off > 0; off >>= 1) { if (t < off) red[t] += red[t + off]; __syncthreads(); }
  if (t == 0) V[i] = (float)sqrt(red[0]);
}

__global__ void k_soft(const float* __restrict__ V, const int* __restrict__ segstart,
                       float* __restrict__ ent, double* __restrict__ seggamma) {
  int g = blockIdx.x; int t = threadIdx.x;
  int s = segstart[g];
  int e = NN;
  for (int gg = g + 1; gg <= NG; ++gg) { int v = segstart[gg]; if (v < e) e = v; }
  if (s >= e) { if (t == 0) seggamma[g] = 0.0; return; }
  __shared__ float fm[256];
  __shared__ double dd[256];
  float m = -3.0e38f;
  for (int i = s + t; i < e; i += 256) m = fmaxf(m, V[i]);
  fm[t] = m; __syncthreads();
  for (int off = 128; off > 0; off >>= 1) { if (t < off) fm[t] = fmaxf(fm[t], fm[t + off]); __syncthreads(); }
  float mx = fm[0];
  __syncthreads();
  double sum = 0.0;
  for (int i = s + t; i < e; i += 256) sum += exp((double)V[i] - (double)mx);
  dd[t] = sum; __syncthreads();
  for (int off = 128; off > 0; off >>= 1) { if (t < off) dd[t] += dd[t + off]; __syncthreads(); }
  double tot = dd[0];
  __syncthreads();
  double gs = 0.0;
  for (int i = s + t; i < e; i += 256) {
    double P = exp((double)V[i] - (double)mx) / tot;
    float ev = (P > 0.0) ? (float)(-P * log(P)) : 0.f;
    ent[i] = ev;
    gs += (double)ev;
  }
  dd[t] = gs; __syncthreads();
  for (int off = 128; off > 0; off >>= 1) { if (t < off) dd[t] += dd[t + off]; __syncthreads(); }
  if (t == 0) seggamma[g] = dd[0];
}

// ---------------- GIN MLPs ----------------
__global__ void k_agg1(const float* __restrict__ ent, const int* __restrict__ rp,
                       const int* __restrict__ col, float* __restrict__ agg) {
  int i = blockIdx.x * blockDim.x + threadIdx.x;
  if (i >= NN) return;
  float a = ent[i];
  for (int e = rp[i]; e < rp[i + 1]; ++e) a += ent[col[e]];
  agg[i] = a;
}

__global__ void k_lin1(const float* __restrict__ agg, const float* __restrict__ w,
                       const float* __restrict__ b, float* __restrict__ t) {
  int idx = blockIdx.x * blockDim.x + threadIdx.x;
  if (idx >= NN * HIDN) return;
  int i = idx >> 7, k = idx & 127;
  float v = agg[i] * w[k] + b[k];
  t[idx] = v > 0.f ? v : 0.f;
}

__global__ void k_bn(const float* __restrict__ t, const float* __restrict__ g,
                     const float* __restrict__ be, float* __restrict__ scale,
                     float* __restrict__ shift) {
  int k = blockIdx.x; int tid = threadIdx.x; // 256 threads per column
  __shared__ double red[256];
  double s = 0.0;
  for (int i = tid; i < NN; i += 256) s += (double)t[i * HIDN + k];
  red[tid] = s; __syncthreads();
  for (int off = 128; off > 0; off >>= 1) { if (tid < off) red[tid] += red[tid + off]; __syncthreads(); }
  double mu = red[0] / NN;
  __syncthreads();
  double v = 0.0;
  for (int i = tid; i < NN; i += 256) { double dv = (double)t[i * HIDN + k] - mu; v += dv * dv; }
  red[tid] = v; __syncthreads();
  for (int off = 128; off > 0; off >>= 1) { if (tid < off) red[tid] += red[tid + off]; __syncthreads(); }
  if (tid == 0) {
    float var = (float)(red[0] / NN);
    float sc = g[k] / sqrtf(var + 1e-5f);
    scale[k] = sc;
    shift[k] = be[k] - (float)mu * sc;
  }
}

template<int PRE, int RELU>
__global__ void k_mm(const float* __restrict__ in, const float* __restrict__ Wm,
                     const float* __restrict__ bias, const float* __restrict__ scale,
                     const float* __restrict__ shift, float* __restrict__ out) {
  __shared__ float ti[8][HIDN];
  int r0 = blockIdx.x * 8; int t = threadIdx.x; // 128 threads
  for (int r = 0; r < 8; ++r) {
    float v = in[(r0 + r) * HIDN + t];
    if (PRE) v = v * scale[t] + shift[t];
    ti[r][t] = v;
  }
  __syncthreads();
  float acc[8];
  #pragma unroll
  for (int r = 0; r < 8; ++r) acc[r] = 0.f;
  for (int k = 0; k < HIDN; ++k) {
    float w = Wm[k * HIDN + t];
    #pragma unroll
    for (int r = 0; r < 8; ++r) acc[r] += ti[r][k] * w;
  }
  for (int r = 0; r < 8; ++r) {
    float v = acc[r] + bias[t];
    if (RELU) v = fmaxf(v, 0.f);
    out[(r0 + r) * HIDN + t] = v;
  }
}

__global__ void k_agg128(const float* __restrict__ h, const int* __restrict__ rp,
                         const int* __restrict__ col, float* __restrict__ agg) {
  int i = blockIdx.x; int t = threadIdx.x; // 128 threads
  float a = h[i * HIDN + t];
  for (int e = rp[i]; e < rp[i + 1]; ++e) a += h[col[e] * HIDN + t];
  agg[i * HIDN + t] = a;
}

__global__ void k_lin3(const float* __restrict__ tn, const float* __restrict__ scale,
                       const float* __restrict__ shift, const float* __restrict__ w32,
                       const float* __restrict__ b32, float* __restrict__ p) {
  int i = blockIdx.x; int t = threadIdx.x; // 128
  float v = (tn[i * HIDN + t] * scale[t] + shift[t]) * w32[t];
  __shared__ float red[HIDN];
  red[t] = v; __syncthreads();
  for (int off = 64; off > 0; off >>= 1) { if (t < off) red[t] += red[t + off]; __syncthreads(); }
  if (t == 0) {
    float h3 = red[0] + b32[0];
    p[i] = 1.f / (1.f + expf(-h3));
  }
}

// ---------------- q0 / e0 + loss ----------------
__global__ void k_q0(const float* __restrict__ p, const float* __restrict__ ent,
                     const int* __restrict__ rp, const int* __restrict__ col,
                     float* __restrict__ q0, float* __restrict__ e0) {
  int i = blockIdx.x * blockDim.x + threadIdx.x;
  if (i >= NN) return;
  float s = 0.f, es = 0.f;
  for (int e = rp[i]; e < rp[i + 1]; ++e) {
    int j = col[e];
    float pj = p[j];
    s += pj; es += ent[j] * pj;
  }
  q0[i] = s; e0[i] = es;
}

__global__ void k_loss(const float* __restrict__ ent, const float* __restrict__ p,
                       const float* __restrict__ q0, const double* __restrict__ seggamma,
                       double* __restrict__ scal) {
  __shared__ double ra[256], rb[256];
  int t = threadIdx.x;
  double a = 0.0, b = 0.0;
  for (int i = t; i < NN; i += 256) { a += (double)ent[i] * (double)p[i]; b += (double)p[i] * (double)q0[i]; }
  ra[t] = a; rb[t] = b; __syncthreads();
  for (int off = 128; off > 0; off >>= 1) {
    if (t < off) { ra[t] += ra[t + off]; rb[t] += rb[t + off]; }
    __syncthreads();
  }
  if (t == 0) {
    double gamma = 0.0;
    for (int g = 0; g < NG; ++g) gamma += seggamma[g];
    scal[0] = gamma; scal[1] = ra[0]; scal[2] = rb[0];
    scal[3] = gamma - ra[0] + rb[0];
  }
}

// ---------------- sort (descending p, stable) ----------------
__global__ void k_sort(const float* __restrict__ p, int* __restrict__ order) {
  __shared__ u64 s[NN];
  int t = threadIdx.x; // 1024
  for (int k = t; k < NN; k += 1024) {
    unsigned b = __float_as_uint(p[k]);
    unsigned ss = (b & 0x80000000u) ? ~b : (b | 0x80000000u);
    s[k] = ((u64)(~ss) << 32) | (unsigned)k;
  }
  __syncthreads();
  for (int k = 2; k <= NN; k <<= 1) {
    for (int j = k >> 1; j > 0; j >>= 1) {
      for (int i = t; i < NN; i += 1024) {
        int ixj = i ^ j;
        if (ixj > i) {
          bool up = ((i & k) == 0);
          u64 a = s[i], b = s[ixj];
          if ((a > b) == up) { s[i] = b; s[ixj] = a; }
        }
      }
      __syncthreads();
    }
  }
  order[t] = (int)(s[t] & 0xFFFFFFFFull);
  order[t + 1024] = (int)(s[t + 1024] & 0xFFFFFFFFull);
}

// ---------------- greedy: speculative batch, register-decided, order-indexed CSR ------
#define DPP2(ctrl)                                                                        \
  a += __int_as_float(__builtin_amdgcn_update_dpp(0, __float_as_int(a), ctrl, 0xf, 0xf, true)); \
  b += __int_as_float(__builtin_amdgcn_update_dpp(0, __float_as_int(b), ctrl, 0xf, 0xf, true));

__device__ __forceinline__ void red2(float& a, float& b) {
  DPP2(0x111)
  DPP2(0x112)
  DPP2(0x114)
  DPP2(0x118)
  DPP2(0x142)
  DPP2(0x143)
  a = __int_as_float(__builtin_amdgcn_readlane(__float_as_int(a), 63));
  b = __int_as_float(__builtin_amdgcn_readlane(__float_as_int(b), 63));
}

__global__ void __launch_bounds__(1024, 1) k_greedy(
    const int* __restrict__ rp, const int* __restrict__ col,
    const int* __restrict__ tp, const int2* __restrict__ tri,
    const int* __restrict__ order, const float* __restrict__ p,
    const float* __restrict__ ent, const float* __restrict__ q0,
    const float* __restrict__ e0, const double* __restrict__ scal,
    u8* __restrict__ selb_g) {
  __shared__ float2 dq[NN];           // 16 KB {d, q}
  __shared__ float2 ee[NN];           // 16 KB {ent, E}
  __shared__ u16 colL[NEDGES];        // 64 KB
  __shared__ u16 ordl[NN];            // 4 KB
  __shared__ uint2 rtO[NN];           // 16 KB order-indexed {rp0|rp1<<16, tp0|tp1<<16}
  __shared__ uint2 rtP[NN + 1];       // 16 KB node-indexed {pack(i), pack(i+1)}
  __shared__ ushort2 triL[TRI_LDS];   // 19 KB
  __shared__ unsigned selL[64];
  __shared__ unsigned maskL[2];
  __shared__ float4 svA[2][16];       // {S1, S2, d0, st}
  __shared__ float svQ[2][16];        // q[idx] at eval time
  int t = threadIdx.x;
  int w = t >> 6, lane = t & 63;

  for (int i = t; i < NN; i += 1024) {
    dq[i] = make_float2(p[i], q0[i]);
    ee[i] = make_float2(ent[i], e0[i]);
    int tv0 = tp[i]; if (tv0 > 65535) tv0 = 65535;
    int tv1 = tp[i + 1]; if (tv1 > 65535) tv1 = 65535;
    rtP[i] = make_uint2((unsigned)rp[i] | ((unsigned)tv0 << 16),
                        (unsigned)rp[i + 1] | ((unsigned)tv1 << 16));
    int oi = order[i];
    ordl[i] = (u16)oi;
    int a0 = rp[oi], a1 = rp[oi + 1];
    int b0 = tp[oi]; if (b0 > 65535) b0 = 65535;
    int b1 = tp[oi + 1]; if (b1 > 65535) b1 = 65535;
    rtO[i] = make_uint2((unsigned)a0 | ((unsigned)a1 << 16),
                        (unsigned)b0 | ((unsigned)b1 << 16));
  }
  for (int i = t; i < NEDGES; i += 1024) colL[i] = (u16)col[i];
  for (int i = t; i < TRI_LDS; i += 1024) {
    int2 ab = tri[i];
    triL[i] = make_ushort2((u16)(ab.x & 2047), (u16)(ab.y & 2047));
  }
  double gamma = scal[0], loss = scal[3];
  double ed = scal[1], dAd = scal[2];
  __syncthreads();
  // register decided bitset: lane l owns nodes [32l, 32l+32); isolated -> pre-selected
  unsigned decided_reg = 0u;
  {
    int base = lane * 32;
    for (int k = 0; k < 32; ++k) {
      int node = base + k;
      if (((rtP[node + 1].x & 0xffffu) - (rtP[node].x & 0xffffu)) == 0u)
        decided_reg |= 1u << k;
    }
    if (w == 0) selL[lane] = decided_reg;
    if (t < 2) maskL[t] = 0u;
  }
  __syncthreads();

  int pos = 0, rc = 0;
  while (pos < NN) {
    int b = rc & 1; ++rc;
    int step = pos + w;
    if (step < NN) {
      int idx = __builtin_amdgcn_readfirstlane((int)ordl[step]);
      unsigned dw = (unsigned)__builtin_amdgcn_readlane((int)decided_reg, idx >> 5);
      if (!((dw >> (idx & 31)) & 1u)) {
        uint2 rt = rtO[step];
        int r0 = rt.x & 0xffffu, r1 = rt.x >> 16;
        int t0 = rt.y & 0xffffu, t1 = rt.y >> 16;
        float2 dqi = dq[idx];
        float2 eei = ee[idx];
        float s2 = 0.f, st = 0.f;
        for (int e = r0 + lane; e < r1; e += 64) {
          float2 v = dq[colL[e]];
          s2 -= v.y * v.x;
        }
        if (t1 <= TRI_LDS) {
          for (int e = t0 + lane; e < t1; e += 64) {
            ushort2 ab = triL[e];
            st += dq[ab.x].x * dq[ab.y].x;
          }
        } else {  // rare overflow: true offsets + pairs from global
          int g0 = tp[idx], g1 = tp[idx + 1];
          if (g0 > TRI_CAP) g0 = TRI_CAP;
          if (g1 > TRI_CAP) g1 = TRI_CAP;
          for (int e = g0 + lane; e < g1; e += 64) {
            int2 ab = tri[e];
            st += dq[ab.x].x * dq[ab.y].x;
          }
        }
        red2(s2, st);
        float d0 = 1.f - dqi.x;
        float S1 = -eei.y + eei.x * d0;
        float S2 = s2 + dqi.y * d0;
        float sn = -dqi.y;
        double cross = 2.0 * (double)d0 * (double)sn + (double)st;
        double li = gamma - (ed + (double)S1) + (dAd + 2.0 * (double)S2 + cross);
        if (li <= loss && lane == 0) {
          svA[b][w] = make_float4(S1, S2, d0, st);
          svQ[b][w] = dqi.y;
          atomicOr(&maskL[b], 1u << w);
        }
      }
    }
    __syncthreads();
    unsigned mask = maskL[b];
    if (mask == 0u) { pos += 16; continue; }
    int k = __builtin_ctz(mask);
    int idx = __builtin_amdgcn_readfirstlane((int)ordl[pos + k]);
    float4 A = svA[b][k];     // {S1, S2, d0, st}
    float qi = svQ[b][k];     // old q[idx] (saved at eval; q unchanged since)
    uint2 rt = rtP[idx];
    int r0 = rt.x & 0xffff, r1 = rt.y & 0xffff;
    int degA = r1 - r0;
    {
      double cross = 2.0 * (double)A.z * (double)(-qi) + (double)A.w;
      ed += (double)A.x;
      dAd += 2.0 * (double)A.y + cross;
    }
    // phase 1: q/E scatter with OLD d (all evals' reads completed at round barrier)
    for (int e = r0 + w; e < r1; e += 16) {
      int a = colL[e];
      float da = -dq[a].x;
      if (da != 0.f) {
        float ea = ee[a].x;
        uint2 art = rtP[a];
        int b0 = art.x & 0xffff, b1 = art.y & 0xffff;
        for (int eb = b0 + lane; eb < b1; eb += 64) {
          int bb = colL[eb];
          atomicAdd(&dq[bb].y, da);
          atomicAdd(&ee[bb].y, ea * da);
        }
      }
    }
    {
      float ei = ee[idx].x;
      for (int e = r0 + t; e < r1; e += 1024) {
        int bb = colL[e];
        atomicAdd(&dq[bb].y, A.z);
        atomicAdd(&ee[bb].y, ei * A.z);
      }
    }
    __syncthreads();
    // phase 2: d updates + sel + mask reset + register decided update
    if (t == 0) {
      dq[idx].x = 1.f;
      atomicOr(&selL[idx >> 5], 1u << (idx & 31));
      maskL[b] = 0u;
    }
    for (int e = r0 + t; e < r1; e += 1024) dq[colL[e]].x = 0.f;
    {
      int colv = idx;
      if (lane < degA) colv = (int)colL[r0 + lane];
      int lim = degA < 64 ? degA : 64;
      for (int l = 0; l < lim; ++l) {
        int j = __builtin_amdgcn_readlane(colv, l);
        decided_reg |= (lane == (j >> 5)) ? (1u << (j & 31)) : 0u;
      }
      for (int l = 64; l < degA; ++l) {  // ultra-rare tail
        int j = (int)colL[r0 + l];
        decided_reg |= (lane == (j >> 5)) ? (1u << (j & 31)) : 0u;
      }
      decided_reg |= (lane == (idx >> 5)) ? (1u << (idx & 31)) : 0u;
    }
    __syncthreads();
    pos = pos + k + 1;
  }
  for (int i = t; i < NN; i += 1024)
    selb_g[i] = (u8)((selL[i >> 5] >> (i & 31)) & 1u);
}

// ---------------- boolean A^2 / A^3 ----------------
__global__ void k_reach(const u64* __restrict__ src, const int* __restrict__ rp,
                        const int* __restrict__ col, u64* __restrict__ dst) {
  int node = blockIdx.x * 2 + (threadIdx.x >> 5);
  int w = threadIdx.x & 31;
  u64 acc = 0;
  for (int e = rp[node]; e < rp[node + 1]; ++e) acc |= src[((size_t)col[e] << 5) + w];
  dst[((size_t)node << 5) + w] = acc;
}

// ---------------- outputs (fused) ----------------
__global__ void k_out(const u64* __restrict__ row2, const u64* __restrict__ row3,
                      const u8* __restrict__ selb, const float* __restrict__ x,
                      const int* __restrict__ batch, const double* __restrict__ scal,
                      float* __restrict__ o_x, float* __restrict__ o_adj,
                      float* __restrict__ o_sel, float* __restrict__ o_bat,
                      float* __restrict__ o_loss) {
  int idx = blockIdx.x * blockDim.x + threadIdx.x; // NN*NN
  {
    int i = idx >> 11, j = idx & 2047;
    int wo = (i << 5) + (j >> 6);
    u64 b = (row2[wo] | row3[wo]) >> (j & 63);
    o_adj[idx] = ((b & 1ull) && i != j && selb[i] && selb[j]) ? 1.f : 0.f;
  }
  if (idx < NN * DIMF) {
    int i = idx >> 8;
    o_x[idx] = selb[i] ? x[idx] : 0.f;
  }
  if (idx < NN) {
    o_sel[idx] = selb[idx] ? 1.f : 0.f;
    o_bat[idx] = selb[idx] ? (float)batch[idx] : -1.f;
  }
  if (idx == 0) o_loss[0] = (float)scal[3];
}

extern "C" void kernel_launch(void* const* d_in, const int* in_sizes, int n_in,
                              void* d_out, int out_size, void* d_ws, size_t ws_size,
                              hipStream_t stream) {
  const float* x    = (const float*)d_in[0];
  const int*   ei   = (const int*)d_in[1];
  const int*   batch= (const int*)d_in[2];
  const float* w11  = (const float*)d_in[3];
  const float* b11  = (const float*)d_in[4];
  const float* g1   = (const float*)d_in[5];
  const float* be1  = (const float*)d_in[6];
  const float* w12  = (const float*)d_in[7];
  const float* b12  = (const float*)d_in[8];
  const float* w21  = (const float*)d_in[9];
  const float* b21  = (const float*)d_in[10];
  const float* g2   = (const float*)d_in[11];
  const float* be2  = (const float*)d_in[12];
  const float* w22  = (const float*)d_in[13];
  const float* b22  = (const float*)d_in[14];
  const float* w31  = (const float*)d_in[15];
  const float* b31  = (const float*)d_in[16];
  const float* g3   = (const float*)d_in[17];
  const float* be3  = (const float*)d_in[18];
  const float* w32  = (const float*)d_in[19];
  const float* b32  = (const float*)d_in[20];

  char* wsb = (char*)d_ws;
  size_t cur = 0;
  auto alloc = [&](size_t bytes) -> void* {
    void* pp = wsb + cur;
    cur += (bytes + 255) & ~(size_t)255;
    return pp;
  };
  u64*    rowbits = (u64*)alloc((size_t)NN * W32 * 8);
  u64*    row2    = (u64*)alloc((size_t)NN * W32 * 8);
  u64*    row3    = (u64*)alloc((size_t)NN * W32 * 8);
  double* seggam  = (double*)alloc(NG * 8);
  double* scal    = (double*)alloc(4 * 8);
  int*    deg     = (int*)alloc(NN * 4);
  int*    rowptr  = (int*)alloc((NN + 1) * 4);
  int*    colx    = (int*)alloc(65536 * 4);
  int*    tricnt  = (int*)alloc(NN * 4);
  int*    triptr  = (int*)alloc((NN + 1) * 4);
  int2*   tri     = (int2*)alloc((size_t)TRI_CAP * 8);
  int*    segst   = (int*)alloc((NG + 1) * 4);
  int*    order   = (int*)alloc(NN * 4);
  float*  ent     = (float*)alloc(NN * 4);
  float*  V       = (float*)alloc(NN * 4);
  float*  p       = (float*)alloc(NN * 4);
  float*  q0      = (float*)alloc(NN * 4);
  float*  e0      = (float*)alloc(NN * 4);
  float*  agg1    = (float*)alloc(NN * 4);
  float*  scale   = (float*)alloc(HIDN * 4);
  float*  shift   = (float*)alloc(HIDN * 4);
  float*  tA      = (float*)alloc((size_t)NN * HIDN * 4);
  float*  tB      = (float*)alloc((size_t)NN * HIDN * 4);
  float*  tC      = (float*)alloc((size_t)NN * HIDN * 4);
  u8*     selb    = (u8*)alloc(NN);

  float* out    = (float*)d_out;
  float* o_x    = out;                       // 524288
  float* o_adj  = out + 524288;              // 4194304
  float* o_sel  = out + 4718592;             // 2048
  float* o_bat  = out + 4720640;             // 2048
  float* o_loss = out + 4722688;             // 1

  k_init<<<64, 256, 0, stream>>>(rowbits, segst);
  k_edges<<<128, 256, 0, stream>>>(ei, rowbits);
  k_deg<<<8, 256, 0, stream>>>(rowbits, deg, batch, segst);
  k_scan2048<<<1, 256, 0, stream>>>(deg, rowptr);
  k_extract<<<8, 256, 0, stream>>>(rowbits, rowptr, colx, tricnt);
  k_scan2048<<<1, 256, 0, stream>>>(tricnt, triptr);
  k_trifill<<<8, 256, 0, stream>>>(rowbits, rowptr, colx, triptr, tri);
  k_V<<<NN, 256, 0, stream>>>(x, rowptr, colx, V);
  k_soft<<<NG, 256, 0, stream>>>(V, segst, ent, seggam);

  // layer 1
  k_agg1<<<8, 256, 0, stream>>>(ent, rowptr, colx, agg1);
  k_lin1<<<1024, 256, 0, stream>>>(agg1, w11, b11, tA);
  k_bn<<<HIDN, 256, 0, stream>>>(tA, g1, be1, scale, shift);
  k_mm<1, 0><<<NN / 8, HIDN, 0, stream>>>(tA, w12, b12, scale, shift, tB);
  // layer 2
  k_agg128<<<NN, HIDN, 0, stream>>>(tB, rowptr, colx, tC);
  k_mm<0, 1><<<NN / 8, HIDN, 0, stream>>>(tC, w21, b21, scale, shift, tA);
  k_bn<<<HIDN, 256, 0, stream>>>(tA, g2, be2, scale, shift);
  k_mm<1, 0><<<NN / 8, HIDN, 0, stream>>>(tA, w22, b22, scale, shift, tB);
  // layer 3
  k_agg128<<<NN, HIDN, 0, stream>>>(tB, rowptr, colx, tC);
  k_mm<0, 1><<<NN / 8, HIDN, 0, stream>>>(tC, w31, b31, scale, shift, tA);
  k_bn<<<HIDN, 256, 0, stream>>>(tA, g3, be3, scale, shift);
  k_lin3<<<NN, HIDN, 0, stream>>>(tA, scale, shift, w32, b32, p);

  k_q0<<<8, 256, 0, stream>>>(p, ent, rowptr, colx, q0, e0);
  k_loss<<<1, 256, 0, stream>>>(ent, p, q0, seggam, scal);
  k_sort<<<1, 1024, 0, stream>>>(p, order);
  k_greedy<<<1, 1024, 0, stream>>>(rowptr, colx, triptr, tri, order, p, ent, q0, e0, scal, selb);

  k_reach<<<NN / 2, 64, 0, stream>>>(rowbits, rowptr, colx, row2);
  k_reach<<<NN / 2, 64, 0, stream>>>(row2, rowptr, colx, row3);
  k_out<<<NN * NN / 256, 256, 0, stream>>>(row2, row3, selb, x, batch, scal,
                                           o_x, o_adj, o_sel, o_bat, o_loss);

  (void)in_sizes; (void)n_in; (void)out_size; (void)ws_size;
}

// Round 10
// 1090.829 us; speedup vs baseline: 1.7830x; 1.2595x over previous
//
#include <hip/hip_runtime.h>
#include <math.h>

#define NN 2048
#define DIMF 256
#define HIDN 128
#define NG 8
#define NEDGES 32768
#define W32 32
#define TRI_CAP 131072
#define TRI_LDS 4864

typedef unsigned long long u64;
typedef unsigned char u8;
typedef unsigned short u16;

// ---------------- build adjacency ----------------
__global__ void k_init(u64* __restrict__ rowbits, int* __restrict__ segstart) {
  int i = blockIdx.x * blockDim.x + threadIdx.x;
  for (int k = i; k < NN * W32; k += gridDim.x * blockDim.x) rowbits[k] = 0ull;
  if (i <= NG) segstart[i] = NN;
}

__global__ void k_edges(const int* __restrict__ ei, u64* __restrict__ rowbits) {
  int e = blockIdx.x * blockDim.x + threadIdx.x;
  if (e >= NEDGES) return;
  int u = ei[e], v = ei[NEDGES + e];
  atomicOr(&rowbits[((size_t)u << 5) + (v >> 6)], 1ull << (v & 63));
}

// deg + segment bounds (fused)
__global__ void k_deg(const u64* __restrict__ rowbits, int* __restrict__ deg,
                      const int* __restrict__ batch, int* __restrict__ segstart) {
  int i = blockIdx.x * blockDim.x + threadIdx.x;
  if (i >= NN) return;
  int c = 0;
  for (int w = 0; w < W32; ++w) c += __popcll(rowbits[(i << 5) + w]);
  deg[i] = c;
  if (i == 0 || batch[i] != batch[i - 1]) segstart[batch[i]] = i;
}

// exclusive scan of 2048 ints -> out[0..2048]
__global__ void k_scan2048(const int* __restrict__ in, int* __restrict__ out) {
  __shared__ int part[256];
  int t = threadIdx.x;
  int v[8]; int s = 0;
  for (int k = 0; k < 8; ++k) { v[k] = in[t * 8 + k]; s += v[k]; }
  part[t] = s;
  __syncthreads();
  for (int off = 1; off < 256; off <<= 1) {
    int y = (t >= off) ? part[t - off] : 0;
    __syncthreads();
    part[t] += y;
    __syncthreads();
  }
  int run = part[t] - s;
  for (int k = 0; k < 8; ++k) { out[t * 8 + k] = run; run += v[k]; }
  if (t == 255) out[NN] = part[255];
}

// extract CSR + count triangle pairs (fused)
__global__ void k_extract(const u64* __restrict__ rowbits, const int* __restrict__ rp,
                          int* __restrict__ col, int* __restrict__ cnt) {
  int i = blockIdx.x * blockDim.x + threadIdx.x;
  if (i >= NN) return;
  const u64* ri = rowbits + ((size_t)i << 5);
  int o = rp[i];
  for (int w = 0; w < W32; ++w) {
    u64 b = ri[w];
    while (b) { col[o++] = (w << 6) + __builtin_ctzll(b); b &= b - 1; }
  }
  int c = 0;
  for (int e = rp[i]; e < o; ++e) {
    const u64* ra = rowbits + ((size_t)col[e] << 5);
    for (int w = 0; w < W32; ++w) c += __popcll(ra[w] & ri[w]);
  }
  cnt[i] = c;
}

__global__ void k_trifill(const u64* __restrict__ rowbits, const int* __restrict__ rp,
                          const int* __restrict__ col, const int* __restrict__ tp,
                          int2* __restrict__ tri) {
  int i = blockIdx.x * blockDim.x + threadIdx.x;
  if (i >= NN) return;
  const u64* ri = rowbits + ((size_t)i << 5);
  int o = tp[i];
  for (int e = rp[i]; e < rp[i + 1]; ++e) {
    int a = col[e];
    const u64* ra = rowbits + ((size_t)a << 5);
    for (int w = 0; w < W32; ++w) {
      u64 b = ra[w] & ri[w];
      while (b) {
        int j = (w << 6) + __builtin_ctzll(b);
        if (o < TRI_CAP) tri[o] = make_int2(a, j);
        ++o;
        b &= b - 1;
      }
    }
  }
}

// ---------------- entropy term ----------------
__global__ void k_V(const float* __restrict__ x, const int* __restrict__ rp,
                    const int* __restrict__ col, float* __restrict__ V) {
  int i = blockIdx.x; int t = threadIdx.x; // 256 threads = dims
  float xi = x[i * DIMF + t];
  float s1 = 0.f, s2 = 0.f;
  int r0 = rp[i], r1 = rp[i + 1];
  for (int e = r0; e < r1; ++e) {
    float xj = x[col[e] * DIMF + t];
    s1 += xj; s2 += xj * xj;
  }
  float dg = (float)(r1 - r0);
  float val = dg * xi * xi - 2.f * xi * s1 + s2;
  __shared__ double red[DIMF];
  red[t] = (double)val * (double)val;
  __syncthreads();
  for (int off = DIMF / 2; off > 0; off >>= 1) { if (t < off) red[t] += red[t + off]; __syncthreads(); }
  if (t == 0) V[i] = (float)sqrt(red[0]);
}

__global__ void k_soft(const float* __restrict__ V, const int* __restrict__ segstart,
                       float* __restrict__ ent, double* __restrict__ seggamma) {
  int g = blockIdx.x; int t = threadIdx.x;
  int s = segstart[g];
  int e = NN;
  for (int gg = g + 1; gg <= NG; ++gg) { int v = segstart[gg]; if (v < e) e = v; }
  if (s >= e) { if (t == 0) seggamma[g] = 0.0; return; }
  __shared__ float fm[256];
  __shared__ double dd[256];
  float m = -3.0e38f;
  for (int i = s + t; i < e; i += 256) m = fmaxf(m, V[i]);
  fm[t] = m; __syncthreads();
  for (int off = 128; off > 0; off >>= 1) { if (t < off) fm[t] = fmaxf(fm[t], fm[t + off]); __syncthreads(); }
  float mx = fm[0];
  __syncthreads();
  double sum = 0.0;
  for (int i = s + t; i < e; i += 256) sum += exp((double)V[i] - (double)mx);
  dd[t] = sum; __syncthreads();
  for (int off = 128; off > 0; off >>= 1) { if (t < off) dd[t] += dd[t + off]; __syncthreads(); }
  double tot = dd[0];
  __syncthreads();
  double gs = 0.0;
  for (int i = s + t; i < e; i += 256) {
    double P = exp((double)V[i] - (double)mx) / tot;
    float ev = (P > 0.0) ? (float)(-P * log(P)) : 0.f;
    ent[i] = ev;
    gs += (double)ev;
  }
  dd[t] = gs; __syncthreads();
  for (int off = 128; off > 0; off >>= 1) { if (t < off) dd[t] += dd[t + off]; __syncthreads(); }
  if (t == 0) seggamma[g] = dd[0];
}

// ---------------- GIN MLPs ----------------
__global__ void k_agg1(const float* __restrict__ ent, const int* __restrict__ rp,
                       const int* __restrict__ col, float* __restrict__ agg) {
  int i = blockIdx.x * blockDim.x + threadIdx.x;
  if (i >= NN) return;
  float a = ent[i];
  for (int e = rp[i]; e < rp[i + 1]; ++e) a += ent[col[e]];
  agg[i] = a;
}

// FROMAGG=1: value = relu(src[i]*w1[k]+b1[k]) computed on the fly (lin1 fused away)
template<int FROMAGG>
__global__ void k_bn(const float* __restrict__ src, const float* __restrict__ w1,
                     const float* __restrict__ b1, const float* __restrict__ g,
                     const float* __restrict__ be, float* __restrict__ scale,
                     float* __restrict__ shift) {
  int k = blockIdx.x; int tid = threadIdx.x; // 256 threads per column
  __shared__ double red[256];
  float wk = 0.f, bk = 0.f;
  if (FROMAGG) { wk = w1[k]; bk = b1[k]; }
  double s = 0.0;
  for (int i = tid; i < NN; i += 256) {
    float v;
    if (FROMAGG) { v = src[i] * wk + bk; v = v > 0.f ? v : 0.f; }
    else v = src[i * HIDN + k];
    s += (double)v;
  }
  red[tid] = s; __syncthreads();
  for (int off = 128; off > 0; off >>= 1) { if (tid < off) red[tid] += red[tid + off]; __syncthreads(); }
  double mu = red[0] / NN;
  __syncthreads();
  double vv = 0.0;
  for (int i = tid; i < NN; i += 256) {
    float v;
    if (FROMAGG) { v = src[i] * wk + bk; v = v > 0.f ? v : 0.f; }
    else v = src[i * HIDN + k];
    double dv = (double)v - mu; vv += dv * dv;
  }
  red[tid] = vv; __syncthreads();
  for (int off = 128; off > 0; off >>= 1) { if (tid < off) red[tid] += red[tid + off]; __syncthreads(); }
  if (tid == 0) {
    float var = (float)(red[0] / NN);
    float sc = g[k] / sqrtf(var + 1e-5f);
    scale[k] = sc;
    shift[k] = be[k] - (float)mu * sc;
  }
}

// PRE: 0 = raw src, 1 = src*scale+shift, 2 = relu(agg[r]*lw+lb)*scale+shift (layer-1 fused)
template<int PRE, int RELU>
__global__ void k_mm(const float* __restrict__ in, const float* __restrict__ Wm,
                     const float* __restrict__ bias, const float* __restrict__ scale,
                     const float* __restrict__ shift, const float* __restrict__ lw,
                     const float* __restrict__ lb, float* __restrict__ out) {
  __shared__ float ti[8][HIDN];
  int r0 = blockIdx.x * 8; int t = threadIdx.x; // 128 threads
  for (int r = 0; r < 8; ++r) {
    float v;
    if (PRE == 2) {
      v = in[r0 + r] * lw[t] + lb[t];
      v = v > 0.f ? v : 0.f;
      v = v * scale[t] + shift[t];
    } else {
      v = in[(r0 + r) * HIDN + t];
      if (PRE == 1) v = v * scale[t] + shift[t];
    }
    ti[r][t] = v;
  }
  __syncthreads();
  float acc[8];
  #pragma unroll
  for (int r = 0; r < 8; ++r) acc[r] = 0.f;
  for (int k = 0; k < HIDN; ++k) {
    float w = Wm[k * HIDN + t];
    #pragma unroll
    for (int r = 0; r < 8; ++r) acc[r] += ti[r][k] * w;
  }
  for (int r = 0; r < 8; ++r) {
    float v = acc[r] + bias[t];
    if (RELU) v = fmaxf(v, 0.f);
    out[(r0 + r) * HIDN + t] = v;
  }
}

__global__ void k_agg128(const float* __restrict__ h, const int* __restrict__ rp,
                         const int* __restrict__ col, float* __restrict__ agg) {
  int i = blockIdx.x; int t = threadIdx.x; // 128 threads
  float a = h[i * HIDN + t];
  for (int e = rp[i]; e < rp[i + 1]; ++e) a += h[col[e] * HIDN + t];
  agg[i * HIDN + t] = a;
}

__global__ void k_lin3(const float* __restrict__ tn, const float* __restrict__ scale,
                       const float* __restrict__ shift, const float* __restrict__ w32,
                       const float* __restrict__ b32, float* __restrict__ p) {
  int i = blockIdx.x; int t = threadIdx.x; // 128
  float v = (tn[i * HIDN + t] * scale[t] + shift[t]) * w32[t];
  __shared__ float red[HIDN];
  red[t] = v; __syncthreads();
  for (int off = 64; off > 0; off >>= 1) { if (t < off) red[t] += red[t + off]; __syncthreads(); }
  if (t == 0) {
    float h3 = red[0] + b32[0];
    p[i] = 1.f / (1.f + expf(-h3));
  }
}

// ---------------- q0 / e0 ----------------
__global__ void k_q0(const float* __restrict__ p, const float* __restrict__ ent,
                     const int* __restrict__ rp, const int* __restrict__ col,
                     float* __restrict__ q0, float* __restrict__ e0) {
  int i = blockIdx.x * blockDim.x + threadIdx.x;
  if (i >= NN) return;
  float s = 0.f, es = 0.f;
  for (int e = rp[i]; e < rp[i + 1]; ++e) {
    int j = col[e];
    float pj = p[j];
    s += pj; es += ent[j] * pj;
  }
  q0[i] = s; e0[i] = es;
}

// ---------------- sort (descending p, stable) + loss finalize (merged) --------------
__global__ void __launch_bounds__(1024, 1) k_sortloss(
    const float* __restrict__ p, const float* __restrict__ ent,
    const float* __restrict__ q0, const double* __restrict__ seggamma,
    double* __restrict__ scal, int* __restrict__ order) {
  __shared__ u64 s[NN];
  __shared__ double rr[32];
  int t = threadIdx.x; // 1024
  double a = 0.0, b = 0.0;
  for (int i = t; i < NN; i += 1024) {
    a += (double)ent[i] * (double)p[i];
    b += (double)p[i] * (double)q0[i];
  }
  for (int off = 32; off; off >>= 1) { a += __shfl_down(a, off); b += __shfl_down(b, off); }
  if ((t & 63) == 0) { rr[(t >> 6) * 2] = a; rr[(t >> 6) * 2 + 1] = b; }
  for (int k = t; k < NN; k += 1024) {
    unsigned bb = __float_as_uint(p[k]);
    unsigned ss = (bb & 0x80000000u) ? ~bb : (bb | 0x80000000u);
    s[k] = ((u64)(~ss) << 32) | (unsigned)k;
  }
  __syncthreads();
  if (t == 0) {
    double A = 0.0, Bb = 0.0, gamma = 0.0;
    for (int i = 0; i < 16; ++i) { A += rr[2 * i]; Bb += rr[2 * i + 1]; }
    for (int g = 0; g < NG; ++g) gamma += seggamma[g];
    scal[0] = gamma; scal[1] = A; scal[2] = Bb; scal[3] = gamma - A + Bb;
  }
  for (int k = 2; k <= NN; k <<= 1) {
    for (int j = k >> 1; j > 0; j >>= 1) {
      for (int i = t; i < NN; i += 1024) {
        int ixj = i ^ j;
        if (ixj > i) {
          bool up = ((i & k) == 0);
          u64 aa = s[i], bb = s[ixj];
          if ((aa > bb) == up) { s[i] = bb; s[ixj] = aa; }
        }
      }
      __syncthreads();
    }
  }
  order[t] = (int)(s[t] & 0xFFFFFFFFull);
  order[t + 1024] = (int)(s[t + 1024] & 0xFFFFFFFFull);
}

// ---------------- greedy: round-5 structure + svQ (one less barrier per accept) -----
#define DPP2(ctrl)                                                                        \
  a += __int_as_float(__builtin_amdgcn_update_dpp(0, __float_as_int(a), ctrl, 0xf, 0xf, true)); \
  b += __int_as_float(__builtin_amdgcn_update_dpp(0, __float_as_int(b), ctrl, 0xf, 0xf, true));

__device__ __forceinline__ void red2(float& a, float& b) {
  DPP2(0x111)
  DPP2(0x112)
  DPP2(0x114)
  DPP2(0x118)
  DPP2(0x142)
  DPP2(0x143)
  a = __int_as_float(__builtin_amdgcn_readlane(__float_as_int(a), 63));
  b = __int_as_float(__builtin_amdgcn_readlane(__float_as_int(b), 63));
}

__global__ void __launch_bounds__(1024, 1) k_greedy(
    const int* __restrict__ rp, const int* __restrict__ col,
    const int* __restrict__ tp, const int2* __restrict__ tri,
    const int* __restrict__ order, const float* __restrict__ p,
    const float* __restrict__ ent, const float* __restrict__ q0,
    const float* __restrict__ e0, const double* __restrict__ scal,
    u8* __restrict__ selb_g) {
  __shared__ float2 dq[NN];           // 16 KB {d, q}
  __shared__ float2 ee[NN];           // 16 KB {ent, E}
  __shared__ u16 colL[NEDGES];        // 64 KB
  __shared__ u16 ordl[NN];            // 4 KB
  __shared__ uint2 rtP[NN + 1];       // 16 KB {rp|tp<<16 at i, at i+1}
  __shared__ ushort2 triL[TRI_LDS];   // 19 KB
  __shared__ unsigned decidedL[64], selL[64];
  __shared__ unsigned maskL[2];
  __shared__ float4 svA[2][16];       // {S1, S2, d0, st}
  __shared__ float svQ[2][16];        // q[idx] saved at eval time
  int t = threadIdx.x;
  int w = t >> 6, lane = t & 63;

  for (int i = t; i < NN; i += 1024) {
    dq[i] = make_float2(p[i], q0[i]);
    ee[i] = make_float2(ent[i], e0[i]);
    ordl[i] = (u16)order[i];
    int tv0 = tp[i]; if (tv0 > 65535) tv0 = 65535;
    int tv1 = tp[i + 1]; if (tv1 > 65535) tv1 = 65535;
    rtP[i] = make_uint2((unsigned)rp[i] | ((unsigned)tv0 << 16),
                        (unsigned)rp[i + 1] | ((unsigned)tv1 << 16));
  }
  for (int i = t; i < NEDGES; i += 1024) colL[i] = (u16)col[i];
  for (int i = t; i < TRI_LDS; i += 1024) {
    int2 ab = tri[i];
    triL[i] = make_ushort2((u16)(ab.x & 2047), (u16)(ab.y & 2047));
  }
  if (t < 64) { decidedL[t] = 0u; selL[t] = 0u; }
  if (t < 2) maskL[t] = 0u;
  double gamma = scal[0], loss = scal[3];
  double ed = scal[1], dAd = scal[2];  // replicated per-thread registers
  __syncthreads();
  // pre-decide isolated nodes (selected; never touched again)
  for (int i = t; i < NN; i += 1024) {
    if (((rtP[i].y & 0xffffu) - (rtP[i].x & 0xffffu)) == 0u) {
      atomicOr(&decidedL[i >> 5], 1u << (i & 31));
      atomicOr(&selL[i >> 5], 1u << (i & 31));
    }
  }
  __syncthreads();

  int pos = 0, rc = 0;
  while (pos < NN) {
    int b = rc & 1; ++rc;
    int step = pos + w;
    if (step < NN) {
      int idx = ordl[step];
      if (!((decidedL[idx >> 5] >> (idx & 31)) & 1u)) {
        uint2 rt = rtP[idx];
        int r0 = rt.x & 0xffff, r1 = rt.y & 0xffff;
        int t0 = rt.x >> 16, t1 = rt.y >> 16;
        float2 dqi = dq[idx];   // broadcast
        float2 eei = ee[idx];   // broadcast
        float s2 = 0.f, st = 0.f;
        for (int e = r0 + lane; e < r1; e += 64) {
          float2 v = dq[colL[e]];
          s2 -= v.y * v.x;
        }
        if (t1 <= TRI_LDS) {
          for (int e = t0 + lane; e < t1; e += 64) {
            ushort2 ab = triL[e];
            st += dq[ab.x].x * dq[ab.y].x;
          }
        } else {  // rare overflow: true offsets + pairs from global
          int g0 = tp[idx], g1 = tp[idx + 1];
          if (g0 > TRI_CAP) g0 = TRI_CAP;
          if (g1 > TRI_CAP) g1 = TRI_CAP;
          for (int e = g0 + lane; e < g1; e += 64) {
            int2 ab = tri[e];
            st += dq[ab.x].x * dq[ab.y].x;
          }
        }
        red2(s2, st);
        float d0 = 1.f - dqi.x;
        float S1 = -eei.y + eei.x * d0;
        float S2 = s2 + dqi.y * d0;
        float sn = -dqi.y;
        double cross = 2.0 * (double)d0 * (double)sn + (double)st;
        double li = gamma - (ed + (double)S1) + (dAd + 2.0 * (double)S2 + cross);
        if (li <= loss && lane == 0) {
          svA[b][w] = make_float4(S1, S2, d0, st);
          svQ[b][w] = dqi.y;
          atomicOr(&maskL[b], 1u << w);
        }
      }
    }
    __syncthreads();
    unsigned mask = maskL[b];
    if (mask == 0u) { pos += 16; continue; }
    int k = __builtin_ctz(mask);
    int idx = ordl[pos + k];
    float4 A = svA[b][k];     // broadcast: {S1, S2, d0, st}
    float qi = svQ[b][k];     // old q[idx], saved at eval (q unchanged since)
    uint2 rt = rtP[idx];
    int r0 = rt.x & 0xffff, r1 = rt.y & 0xffff;
    // all threads replicate scalar updates (identical f64 ops -> consistent)
    {
      double cross = 2.0 * (double)A.z * (double)(-qi) + (double)A.w;
      ed += (double)A.x;
      dAd += 2.0 * (double)A.y + cross;
    }
    // phase 1: q/E scatter with OLD d (all eval reads completed at round barrier)
    for (int e = r0 + w; e < r1; e += 16) {
      int a = colL[e];
      float da = -dq[a].x;
      if (da != 0.f) {
        float ea = ee[a].x;
        uint2 art = rtP[a];
        int b0 = art.x & 0xffff, b1 = art.y & 0xffff;
        for (int eb = b0 + lane; eb < b1; eb += 64) {
          int bb = colL[eb];
          atomicAdd(&dq[bb].y, da);
          atomicAdd(&ee[bb].y, ea * da);
        }
      }
    }
    {
      float ei = ee[idx].x;
      for (int e = r0 + t; e < r1; e += 1024) {
        int bb = colL[e];
        atomicAdd(&dq[bb].y, A.z);
        atomicAdd(&ee[bb].y, ei * A.z);
      }
    }
    __syncthreads();
    // phase 2: d updates + decided/sel bits + mask reset
    if (t == 0) {
      dq[idx].x = 1.f;
      atomicOr(&decidedL[idx >> 5], 1u << (idx & 31));
      atomicOr(&selL[idx >> 5], 1u << (idx & 31));
      maskL[b] = 0u;
    }
    for (int e = r0 + t; e < r1; e += 1024) {
      int j = colL[e];
      dq[j].x = 0.f;
      atomicOr(&decidedL[j >> 5], 1u << (j & 31));
    }
    __syncthreads();
    pos = pos + k + 1;
  }
  for (int i = t; i < NN; i += 1024)
    selb_g[i] = (u8)((selL[i >> 5] >> (i & 31)) & 1u);
}

// ---------------- boolean A^2 / A^3 ----------------
__global__ void k_reach(const u64* __restrict__ src, const int* __restrict__ rp,
                        const int* __restrict__ col, u64* __restrict__ dst) {
  int node = blockIdx.x * 2 + (threadIdx.x >> 5);
  int w = threadIdx.x & 31;
  u64 acc = 0;
  for (int e = rp[node]; e < rp[node + 1]; ++e) acc |= src[((size_t)col[e] << 5) + w];
  dst[((size_t)node << 5) + w] = acc;
}

// ---------------- outputs (fused) ----------------
__global__ void k_out(const u64* __restrict__ row2, const u64* __restrict__ row3,
                      const u8* __restrict__ selb, const float* __restrict__ x,
                      const int* __restrict__ batch, const double* __restrict__ scal,
                      float* __restrict__ o_x, float* __restrict__ o_adj,
                      float* __restrict__ o_sel, float* __restrict__ o_bat,
                      float* __restrict__ o_loss) {
  int idx = blockIdx.x * blockDim.x + threadIdx.x; // NN*NN
  {
    int i = idx >> 11, j = idx & 2047;
    int wo = (i << 5) + (j >> 6);
    u64 b = (row2[wo] | row3[wo]) >> (j & 63);
    o_adj[idx] = ((b & 1ull) && i != j && selb[i] && selb[j]) ? 1.f : 0.f;
  }
  if (idx < NN * DIMF) {
    int i = idx >> 8;
    o_x[idx] = selb[i] ? x[idx] : 0.f;
  }
  if (idx < NN) {
    o_sel[idx] = selb[idx] ? 1.f : 0.f;
    o_bat[idx] = selb[idx] ? (float)batch[idx] : -1.f;
  }
  if (idx == 0) o_loss[0] = (float)scal[3];
}

extern "C" void kernel_launch(void* const* d_in, const int* in_sizes, int n_in,
                              void* d_out, int out_size, void* d_ws, size_t ws_size,
                              hipStream_t stream) {
  const float* x    = (const float*)d_in[0];
  const int*   ei   = (const int*)d_in[1];
  const int*   batch= (const int*)d_in[2];
  const float* w11  = (const float*)d_in[3];
  const float* b11  = (const float*)d_in[4];
  const float* g1   = (const float*)d_in[5];
  const float* be1  = (const float*)d_in[6];
  const float* w12  = (const float*)d_in[7];
  const float* b12  = (const float*)d_in[8];
  const float* w21  = (const float*)d_in[9];
  const float* b21  = (const float*)d_in[10];
  const float* g2   = (const float*)d_in[11];
  const float* be2  = (const float*)d_in[12];
  const float* w22  = (const float*)d_in[13];
  const float* b22  = (const float*)d_in[14];
  const float* w31  = (const float*)d_in[15];
  const float* b31  = (const float*)d_in[16];
  const float* g3   = (const float*)d_in[17];
  const float* be3  = (const float*)d_in[18];
  const float* w32  = (const float*)d_in[19];
  const float* b32  = (const float*)d_in[20];

  char* wsb = (char*)d_ws;
  size_t cur = 0;
  auto alloc = [&](size_t bytes) -> void* {
    void* pp = wsb + cur;
    cur += (bytes + 255) & ~(size_t)255;
    return pp;
  };
  u64*    rowbits = (u64*)alloc((size_t)NN * W32 * 8);
  u64*    row2    = (u64*)alloc((size_t)NN * W32 * 8);
  u64*    row3    = (u64*)alloc((size_t)NN * W32 * 8);
  double* seggam  = (double*)alloc(NG * 8);
  double* scal    = (double*)alloc(4 * 8);
  int*    deg     = (int*)alloc(NN * 4);
  int*    rowptr  = (int*)alloc((NN + 1) * 4);
  int*    colx    = (int*)alloc(65536 * 4);
  int*    tricnt  = (int*)alloc(NN * 4);
  int*    triptr  = (int*)alloc((NN + 1) * 4);
  int2*   tri     = (int2*)alloc((size_t)TRI_CAP * 8);
  int*    segst   = (int*)alloc((NG + 1) * 4);
  int*    order   = (int*)alloc(NN * 4);
  float*  ent     = (float*)alloc(NN * 4);
  float*  V       = (float*)alloc(NN * 4);
  float*  p       = (float*)alloc(NN * 4);
  float*  q0      = (float*)alloc(NN * 4);
  float*  e0      = (float*)alloc(NN * 4);
  float*  agg1    = (float*)alloc(NN * 4);
  float*  scale   = (float*)alloc(HIDN * 4);
  float*  shift   = (float*)alloc(HIDN * 4);
  float*  tA      = (float*)alloc((size_t)NN * HIDN * 4);
  float*  tB      = (float*)alloc((size_t)NN * HIDN * 4);
  float*  tC      = (float*)alloc((size_t)NN * HIDN * 4);
  u8*     selb    = (u8*)alloc(NN);

  float* out    = (float*)d_out;
  float* o_x    = out;                       // 524288
  float* o_adj  = out + 524288;              // 4194304
  float* o_sel  = out + 4718592;             // 2048
  float* o_bat  = out + 4720640;             // 2048
  float* o_loss = out + 4722688;             // 1

  k_init<<<64, 256, 0, stream>>>(rowbits, segst);
  k_edges<<<128, 256, 0, stream>>>(ei, rowbits);
  k_deg<<<8, 256, 0, stream>>>(rowbits, deg, batch, segst);
  k_scan2048<<<1, 256, 0, stream>>>(deg, rowptr);
  k_extract<<<8, 256, 0, stream>>>(rowbits, rowptr, colx, tricnt);
  k_scan2048<<<1, 256, 0, stream>>>(tricnt, triptr);
  k_trifill<<<8, 256, 0, stream>>>(rowbits, rowptr, colx, triptr, tri);
  k_V<<<NN, 256, 0, stream>>>(x, rowptr, colx, V);
  k_soft<<<NG, 256, 0, stream>>>(V, segst, ent, seggam);

  // layer 1 (lin1 fused into bn1 + mm1)
  k_agg1<<<8, 256, 0, stream>>>(ent, rowptr, colx, agg1);
  k_bn<1><<<HIDN, 256, 0, stream>>>(agg1, w11, b11, g1, be1, scale, shift);
  k_mm<2, 0><<<NN / 8, HIDN, 0, stream>>>(agg1, w12, b12, scale, shift, w11, b11, tB);
  // layer 2
  k_agg128<<<NN, HIDN, 0, stream>>>(tB, rowptr, colx, tC);
  k_mm<0, 1><<<NN / 8, HIDN, 0, stream>>>(tC, w21, b21, scale, shift, (const float*)0, (const float*)0, tA);
  k_bn<0><<<HIDN, 256, 0, stream>>>(tA, (const float*)0, (const float*)0, g2, be2, scale, shift);
  k_mm<1, 0><<<NN / 8, HIDN, 0, stream>>>(tA, w22, b22, scale, shift, (const float*)0, (const float*)0, tB);
  // layer 3
  k_agg128<<<NN, HIDN, 0, stream>>>(tB, rowptr, colx, tC);
  k_mm<0, 1><<<NN / 8, HIDN, 0, stream>>>(tC, w31, b31, scale, shift, (const float*)0, (const float*)0, tA);
  k_bn<0><<<HIDN, 256, 0, stream>>>(tA, (const float*)0, (const float*)0, g3, be3, scale, shift);
  k_lin3<<<NN, HIDN, 0, stream>>>(tA, scale, shift, w32, b32, p);

  k_q0<<<8, 256, 0, stream>>>(p, ent, rowptr, colx, q0, e0);
  k_sortloss<<<1, 1024, 0, stream>>>(p, ent, q0, seggam, scal, order);
  k_greedy<<<1, 1024, 0, stream>>>(rowptr, colx, triptr, tri, order, p, ent, q0, e0, scal, selb);

  k_reach<<<NN / 2, 64, 0, stream>>>(rowbits, rowptr, colx, row2);
  k_reach<<<NN / 2, 64, 0, stream>>>(row2, rowptr, colx, row3);
  k_out<<<NN * NN / 256, 256, 0, stream>>>(row2, row3, selb, x, batch, scal,
                                           o_x, o_adj, o_sel, o_bat, o_loss);

  (void)in_sizes; (void)n_in; (void)out_size; (void)ws_size;
}